// Round 5
// baseline (2569.290 us; speedup 1.0000x reference)
//
#include <hip/hip_runtime.h>
#include <cstddef>

#define TPB 256

static __device__ __forceinline__ float sigmoidf_(float x) {
  return 1.0f / (1.0f + expf(-x));
}

// ---------------------------------------------------------------------------
// build G = I + A and X0 = I - A, where A = (v - v^T)re + i(v + v^T)im
// ---------------------------------------------------------------------------
__global__ __launch_bounds__(TPB) void build_gx_k(
    const float* __restrict__ vre, const float* __restrict__ vim,
    float* __restrict__ Gr, float* __restrict__ Gi,
    float* __restrict__ Xr, float* __restrict__ Xi)
{
  int idx = blockIdx.x * TPB + threadIdx.x;
  int i = idx >> 10, j = idx & 1023;
  float ar = vre[idx] - vre[j * 1024 + i];
  float ai = vim[idx] + vim[j * 1024 + i];
  float dg = (i == j) ? 1.0f : 0.0f;
  Gr[idx] = dg + ar;  Gi[idx] = ai;
  Xr[idx] = dg - ar;  Xi[idx] = -ai;
}

// ---------------------------------------------------------------------------
// complex GEMM (1024^3, NN): mode 0: C = A@B
//                            mode 1: C = 2I - A@B
//                            mode 2: C = 2A - A@B   (A reloaded at (row,col))
// ---------------------------------------------------------------------------
__global__ __launch_bounds__(TPB) void cgemm_k(
    const float* __restrict__ Ar, const float* __restrict__ Ai,
    const float* __restrict__ Br, const float* __restrict__ Bi,
    float* __restrict__ Cr, float* __restrict__ Ci, int mode)
{
  __shared__ float Asr[64][17], Asi[64][17];
  __shared__ float Bsr[16][64], Bsi[16][64];
  int tid = threadIdx.x;
  int tx = tid & 15, ty = tid >> 4;
  int bm = blockIdx.y * 64, bn = blockIdx.x * 64;
  float accr[4][4] = {{0.0f}}, acci[4][4] = {{0.0f}};
  int lr = tid >> 2, lkq = (tid & 3) << 2;
  int lkk = tid >> 4, lnq = (tid & 15) << 2;
  for (int k0 = 0; k0 < 1024; k0 += 16) {
    float4 a0 = *(const float4*)(Ar + (size_t)(bm + lr) * 1024 + k0 + lkq);
    float4 a1 = *(const float4*)(Ai + (size_t)(bm + lr) * 1024 + k0 + lkq);
    Asr[lr][lkq] = a0.x; Asr[lr][lkq + 1] = a0.y; Asr[lr][lkq + 2] = a0.z; Asr[lr][lkq + 3] = a0.w;
    Asi[lr][lkq] = a1.x; Asi[lr][lkq + 1] = a1.y; Asi[lr][lkq + 2] = a1.z; Asi[lr][lkq + 3] = a1.w;
    float4 b0 = *(const float4*)(Br + (size_t)(k0 + lkk) * 1024 + bn + lnq);
    float4 b1 = *(const float4*)(Bi + (size_t)(k0 + lkk) * 1024 + bn + lnq);
    *(float4*)&Bsr[lkk][lnq] = b0;
    *(float4*)&Bsi[lkk][lnq] = b1;
    __syncthreads();
    #pragma unroll
    for (int kk = 0; kk < 16; ++kk) {
      float ar4[4], ai4[4], br4[4], bi4[4];
      #pragma unroll
      for (int m = 0; m < 4; ++m) { ar4[m] = Asr[ty + 16 * m][kk]; ai4[m] = Asi[ty + 16 * m][kk]; }
      #pragma unroll
      for (int n = 0; n < 4; ++n) { br4[n] = Bsr[kk][tx + 16 * n]; bi4[n] = Bsi[kk][tx + 16 * n]; }
      #pragma unroll
      for (int m = 0; m < 4; ++m) {
        #pragma unroll
        for (int n = 0; n < 4; ++n) {
          accr[m][n] += ar4[m] * br4[n] - ai4[m] * bi4[n];
          acci[m][n] += ar4[m] * bi4[n] + ai4[m] * br4[n];
        }
      }
    }
    __syncthreads();
  }
  #pragma unroll
  for (int m = 0; m < 4; ++m) {
    int row = bm + ty + 16 * m;
    #pragma unroll
    for (int n = 0; n < 4; ++n) {
      int col = bn + tx + 16 * n;
      float vr = accr[m][n], vi = acci[m][n];
      if (mode == 1) { vr = ((row == col) ? 2.0f : 0.0f) - vr; vi = -vi; }
      if (mode == 2) {
        size_t o = (size_t)row * 1024 + col;
        vr = 2.0f * Ar[o] - vr;  vi = 2.0f * Ai[o] - vi;
      }
      Cr[(size_t)row * 1024 + col] = vr;
      Ci[(size_t)row * 1024 + col] = vi;
    }
  }
}

// ---------------------------------------------------------------------------
// M = V*diag(exp(log_sigma))*(1-alpha) + F*alpha   (F = DFT basis / 32)
// ---------------------------------------------------------------------------
__global__ __launch_bounds__(TPB) void build_m_k(
    const float* __restrict__ Vr, const float* __restrict__ Vi,
    const float* __restrict__ log_sigma, const float* __restrict__ dft_weight,
    float* __restrict__ Mr, float* __restrict__ Mi)
{
  int idx = blockIdx.x * TPB + threadIdx.x;
  int k = idx >> 10, dp = idx & 1023;
  float alpha = sigmoidf_(dft_weight[0]);
  float w1 = expf(log_sigma[dp]) * (1.0f - alpha);
  int mm = (k * dp) & 1023;                       // exact angle reduction
  float ang = -6.283185307179586f * (float)mm * (1.0f / 1024.0f);
  float sn, cs;
  sincosf(ang, &sn, &cs);
  const float isq = 0.03125f * alpha;             // alpha / sqrt(1024)
  Mr[idx] = Vr[idx] * w1 + cs * isq;
  Mi[idx] = Vi[idx] * w1 + sn * isq;
}

// ---------------------------------------------------------------------------
// per-d constants: op_decay, op_forcing, base_var
// ---------------------------------------------------------------------------
__global__ __launch_bounds__(TPB) void prep_k(
    const float* __restrict__ ld, const float* __restrict__ lf,
    const float* __restrict__ law_re, const float* __restrict__ law_im,
    const float* __restrict__ dt, const float* __restrict__ base_noise,
    float* __restrict__ od_re, float* __restrict__ od_im,
    float* __restrict__ of_re, float* __restrict__ of_im,
    float* __restrict__ bvar)
{
  int d = blockIdx.x * TPB + threadIdx.x;
  float dtr = dt[0];                              // DT_REF = 1.0
  float lre = tanhf(-expf(ld[d]) + law_re[d]) * 0.3f;
  float lim = lf[d] + law_im[d];
  float er = expf(lre * dtr);
  float sn, cs;
  sincosf(lim * dtr, &sn, &cs);
  float odr = er * cs, odi = er * sn;
  od_re[d] = odr;  od_im[d] = odi;
  float numr = odr - 1.0f, numi = odi;
  float denr = lre + 1e-8f, deni = lim;
  float inv = 1.0f / (denr * denr + deni * deni);
  of_re[d] = (numr * denr + numi * deni) * inv;
  of_im[d] = (numi * denr - numr * deni) * inv;
  float bn = base_noise[0];
  float bv = bn * bn * expm1f(2.0f * lre * dtr) / (2.0f * lre + 1e-8f);
  bvar[d] = fmaxf(bv, 0.0f);
}

// ---------------------------------------------------------------------------
// small (16 x N) gemm: C[r,c] = sum_k [A0|A1][r,k] * Bw[c,k] + bias[c]
// ---------------------------------------------------------------------------
__global__ __launch_bounds__(TPB) void small_gemm_k(
    const float* __restrict__ A0, const float* __restrict__ A1,
    const float* __restrict__ Bw, const float* __restrict__ bias,
    float* __restrict__ C, int N, int act)
{
  int c = blockIdx.x * TPB + threadIdx.x;
  int r0 = blockIdx.y * 4;
  float acc[4] = {0.0f, 0.0f, 0.0f, 0.0f};
  const float* brow = Bw + (size_t)c * 2048;
  for (int k = 0; k < 1024; k += 4) {
    float4 b0 = *(const float4*)(brow + k);
    float4 b1 = *(const float4*)(brow + 1024 + k);
    #pragma unroll
    for (int r = 0; r < 4; ++r) {
      const float* a0 = A0 + (size_t)(r0 + r) * 1024 + k;
      const float* a1 = A1 + (size_t)(r0 + r) * 1024 + k;
      acc[r] += a0[0] * b0.x + a0[1] * b0.y + a0[2] * b0.z + a0[3] * b0.w
              + a1[0] * b1.x + a1[1] * b1.y + a1[2] * b1.z + a1[3] * b1.w;
    }
  }
  #pragma unroll
  for (int r = 0; r < 4; ++r) {
    float v = acc[r] + bias[c];
    if (act == 1) v = sigmoidf_(v);
    C[(size_t)(r0 + r) * N + c] = v;
  }
}

// ---------------------------------------------------------------------------
// flux_next = flux*fdecay + update ; FN planes + f32 output 1 = Re(flux_next)
// ---------------------------------------------------------------------------
__global__ __launch_bounds__(TPB) void flux_k(
    const float* __restrict__ xin,
    const float* __restrict__ flux_re, const float* __restrict__ flux_im,
    const float* __restrict__ decay_re, const float* __restrict__ decay_im,
    float* __restrict__ FNr, float* __restrict__ FNi,
    float* __restrict__ out1)
{
  int idx = blockIdx.x * TPB + threadIdx.x;     // 16 * 1024
  int b = idx >> 10, d = idx & 1023;
  float fdr = sigmoidf_(decay_re[d]);
  float fdi = decay_im[d];
  float fr = flux_re[idx], fi = flux_im[idx];
  float ur = xin[b * 2048 + d], ui = xin[b * 2048 + 1024 + d];
  float nr = fr * fdr - fi * fdi + ur;
  float ni = fr * fdi + fi * fdr + ui;
  FNr[idx] = nr;  FNi[idx] = ni;
  out1[idx] = nr;                                // f32, real part only
}

// ---------------------------------------------------------------------------
// fused: x_tilde = x @ M (complex), h_next epilogue -> Hr (real part only)
// ---------------------------------------------------------------------------
__global__ __launch_bounds__(TPB) void xmh_k(
    const float* __restrict__ Xin,
    const float* __restrict__ Mr, const float* __restrict__ Mi,
    const float* __restrict__ gate, const float* __restrict__ proj,
    const float* __restrict__ od_re, const float* __restrict__ od_im,
    const float* __restrict__ of_re, const float* __restrict__ of_im,
    const float* __restrict__ hp_re, const float* __restrict__ hp_im,
    float* __restrict__ Hr)
{
  __shared__ float As[64][17];
  __shared__ float Bsr[16][64], Bsi[16][64];
  int tid = threadIdx.x;
  int tx = tid & 15, ty = tid >> 4;
  int bm = blockIdx.y * 64, bn = blockIdx.x * 64;
  float ac_r[4][4] = {{0.0f}}, ac_i[4][4] = {{0.0f}};
  int lr = tid >> 2, lkq = (tid & 3) << 2;
  int lkk = tid >> 4, lnq = (tid & 15) << 2;
  for (int k0 = 0; k0 < 1024; k0 += 16) {
    float4 a0 = *(const float4*)(Xin + (size_t)(bm + lr) * 1024 + k0 + lkq);
    As[lr][lkq] = a0.x; As[lr][lkq + 1] = a0.y; As[lr][lkq + 2] = a0.z; As[lr][lkq + 3] = a0.w;
    float4 b0 = *(const float4*)(Mr + (size_t)(k0 + lkk) * 1024 + bn + lnq);
    float4 b1 = *(const float4*)(Mi + (size_t)(k0 + lkk) * 1024 + bn + lnq);
    *(float4*)&Bsr[lkk][lnq] = b0;
    *(float4*)&Bsi[lkk][lnq] = b1;
    __syncthreads();
    #pragma unroll
    for (int kk = 0; kk < 16; ++kk) {
      float a4[4], br4[4], bi4[4];
      #pragma unroll
      for (int m = 0; m < 4; ++m) a4[m] = As[ty + 16 * m][kk];
      #pragma unroll
      for (int n = 0; n < 4; ++n) { br4[n] = Bsr[kk][tx + 16 * n]; bi4[n] = Bsi[kk][tx + 16 * n]; }
      #pragma unroll
      for (int m = 0; m < 4; ++m) {
        #pragma unroll
        for (int n = 0; n < 4; ++n) {
          ac_r[m][n] += a4[m] * br4[n];
          ac_i[m][n] += a4[m] * bi4[n];
        }
      }
    }
    __syncthreads();
  }
  int b = bm >> 8;                                // 64-row tile never straddles a batch
  #pragma unroll
  for (int m = 0; m < 4; ++m) {
    int t = bm + ty + 16 * m;
    #pragma unroll
    for (int n = 0; n < 4; ++n) {
      int c = bn + tx + 16 * n;
      float g  = gate[b * 1024 + c];
      float sr = proj[b * 2048 + c];
      float si = proj[b * 2048 + 1024 + c];
      float fr = ac_r[m][n] * g + sr * (1.0f - g);
      float fi = ac_i[m][n] * g + si * (1.0f - g);
      float odr = od_re[c], odi = od_im[c];
      float ofr = of_re[c], ofi = of_im[c];
      size_t off = (size_t)t * 1024 + c;
      float pr = hp_re[off], pi = hp_im[off];
      Hr[off] = pr * odr - pi * odi + fr * ofr - fi * ofi;   // real part only
    }
  }
}

// ---------------------------------------------------------------------------
// mlp1 = silu(Hr @ Wu1^T + bu1)    (4096x1024 @ 1024x256)
// ---------------------------------------------------------------------------
__global__ __launch_bounds__(TPB) void mlp1_k(
    const float* __restrict__ A, const float* __restrict__ Bw,
    const float* __restrict__ bias, float* __restrict__ C)
{
  __shared__ float As[64][17], Bs[64][17];
  int tid = threadIdx.x;
  int tx = tid & 15, ty = tid >> 4;
  int bm = blockIdx.y * 64, bn = blockIdx.x * 64;
  float acc[4][4] = {{0.0f}};
  int lr = tid >> 2, lkq = (tid & 3) << 2;
  for (int k0 = 0; k0 < 1024; k0 += 16) {
    float4 a0 = *(const float4*)(A  + (size_t)(bm + lr) * 1024 + k0 + lkq);
    float4 b0 = *(const float4*)(Bw + (size_t)(bn + lr) * 1024 + k0 + lkq);
    As[lr][lkq] = a0.x; As[lr][lkq + 1] = a0.y; As[lr][lkq + 2] = a0.z; As[lr][lkq + 3] = a0.w;
    Bs[lr][lkq] = b0.x; Bs[lr][lkq + 1] = b0.y; Bs[lr][lkq + 2] = b0.z; Bs[lr][lkq + 3] = b0.w;
    __syncthreads();
    #pragma unroll
    for (int kk = 0; kk < 16; ++kk) {
      float a4[4], b4[4];
      #pragma unroll
      for (int m = 0; m < 4; ++m) a4[m] = As[ty + 16 * m][kk];
      #pragma unroll
      for (int n = 0; n < 4; ++n) b4[n] = Bs[tx + 16 * n][kk];
      #pragma unroll
      for (int m = 0; m < 4; ++m) {
        #pragma unroll
        for (int n = 0; n < 4; ++n) acc[m][n] += a4[m] * b4[n];
      }
    }
    __syncthreads();
  }
  #pragma unroll
  for (int m = 0; m < 4; ++m) {
    int t = bm + ty + 16 * m;
    #pragma unroll
    for (int n = 0; n < 4; ++n) {
      int c = bn + tx + 16 * n;
      float v = acc[m][n] + bias[c];
      v = v * sigmoidf_(v);                       // silu
      C[(size_t)t * 256 + c] = v;
    }
  }
}

// ---------------------------------------------------------------------------
// u = softplus(mlp1 @ Wu2^T + bu2); out0 = f32(Re(h) + noise_re*std)
// ---------------------------------------------------------------------------
__global__ __launch_bounds__(TPB) void final_k(
    const float* __restrict__ A, const float* __restrict__ Bw,
    const float* __restrict__ bias,
    const float* __restrict__ Hr,
    const float* __restrict__ nre,
    const float* __restrict__ bvar,
    float* __restrict__ out0)
{
  __shared__ float As[64][17], Bs[64][17];
  int tid = threadIdx.x;
  int tx = tid & 15, ty = tid >> 4;
  int bm = blockIdx.y * 64, bn = blockIdx.x * 64;
  float acc[4][4] = {{0.0f}};
  int lr = tid >> 2, lkq = (tid & 3) << 2;
  for (int k0 = 0; k0 < 256; k0 += 16) {
    float4 a0 = *(const float4*)(A  + (size_t)(bm + lr) * 256 + k0 + lkq);
    float4 b0 = *(const float4*)(Bw + (size_t)(bn + lr) * 256 + k0 + lkq);
    As[lr][lkq] = a0.x; As[lr][lkq + 1] = a0.y; As[lr][lkq + 2] = a0.z; As[lr][lkq + 3] = a0.w;
    Bs[lr][lkq] = b0.x; Bs[lr][lkq + 1] = b0.y; Bs[lr][lkq + 2] = b0.z; Bs[lr][lkq + 3] = b0.w;
    __syncthreads();
    #pragma unroll
    for (int kk = 0; kk < 16; ++kk) {
      float a4[4], b4[4];
      #pragma unroll
      for (int m = 0; m < 4; ++m) a4[m] = As[ty + 16 * m][kk];
      #pragma unroll
      for (int n = 0; n < 4; ++n) b4[n] = Bs[tx + 16 * n][kk];
      #pragma unroll
      for (int m = 0; m < 4; ++m) {
        #pragma unroll
        for (int n = 0; n < 4; ++n) acc[m][n] += a4[m] * b4[n];
      }
    }
    __syncthreads();
  }
  #pragma unroll
  for (int m = 0; m < 4; ++m) {
    int t = bm + ty + 16 * m;
    #pragma unroll
    for (int n = 0; n < 4; ++n) {
      int c = bn + tx + 16 * n;
      float v = acc[m][n] + bias[c];
      float u = (v > 20.0f) ? v : log1pf(expf(v));    // softplus
      float sc = sqrtf(bvar[c] * u) * 0.7071067811865476f;
      size_t off = (size_t)t * 1024 + c;
      out0[off] = Hr[off] + nre[off] * sc;            // f32, real part only
    }
  }
}

// ---------------------------------------------------------------------------
extern "C" void kernel_launch(void* const* d_in, const int* in_sizes, int n_in,
                              void* d_out, int out_size, void* d_ws, size_t ws_size,
                              hipStream_t stream) {
  (void)in_sizes; (void)n_in; (void)out_size;

  const float* x_input    = (const float*)d_in[0];
  const float* h_prev_re  = (const float*)d_in[1];
  const float* h_prev_im  = (const float*)d_in[2];
  const float* xg_re      = (const float*)d_in[3];
  const float* xg_im      = (const float*)d_in[4];
  const float* flux_re    = (const float*)d_in[5];
  const float* flux_im    = (const float*)d_in[6];
  const float* dt         = (const float*)d_in[7];
  const float* v_raw_re   = (const float*)d_in[10];
  const float* v_raw_im   = (const float*)d_in[11];
  const float* log_sigma  = (const float*)d_in[12];
  const float* dft_weight = (const float*)d_in[13];
  const float* decay_re   = (const float*)d_in[14];
  const float* decay_im   = (const float*)d_in[15];
  const float* Wi_in      = (const float*)d_in[16];
  const float* bi         = (const float*)d_in[17];
  const float* Wo         = (const float*)d_in[18];
  const float* bo         = (const float*)d_in[19];
  const float* Wg         = (const float*)d_in[20];
  const float* bg         = (const float*)d_in[21];
  const float* ld         = (const float*)d_in[22];
  const float* lf         = (const float*)d_in[23];
  const float* law_re     = (const float*)d_in[24];
  const float* law_im     = (const float*)d_in[25];
  const float* base_noise = (const float*)d_in[26];
  const float* Wu1        = (const float*)d_in[27];
  const float* bu1        = (const float*)d_in[28];
  const float* Wu2        = (const float*)d_in[29];
  const float* bu2        = (const float*)d_in[30];
  const float* noise_re   = (const float*)d_in[31];

  // --- workspace: 10 planes of 1M floats + smalls ---------------------------
  const size_t PL = 1024ull * 1024ull;
  const size_t SMALL = 2 * 32768 + 3 * 16384 + 5 * 1024;
  if (ws_size < (10 * PL + SMALL) * 4) return;  // too small -> zeros (diagnostic)

  float* w = (float*)d_ws;
  float* Gr = w + 0 * PL;  float* Gi = w + 1 * PL;   // G; -> M after Newton
  float* Pr = w + 2 * PL;  float* Pi = w + 3 * PL;   // X ping
  float* Qr = w + 4 * PL;  float* Qi = w + 5 * PL;   // X pong
  float* Yr = w + 6 * PL;  float* Yi = w + 7 * PL;   // Newton temp
  float* Vr = w + 8 * PL;  float* Vi = w + 9 * PL;   // V result
  float* Mr = Gr;          float* Mi = Gi;           // M overwrites G
  float* Hr = w + 2 * PL;                            // 4 planes (P,Q dead)
  float* mlp1 = w + 6 * PL;                          // 1 plane (Y dead)
  float* xin  = w + 10 * PL;            // 16x2048
  float* proj = xin + 32768;            // 16x2048
  float* FNr  = proj + 32768;           // 16x1024
  float* FNi  = FNr + 16384;
  float* gate = FNi + 16384;            // 16x1024
  float* od_re = gate + 16384;
  float* od_im = od_re + 1024;
  float* of_re = od_im + 1024;
  float* of_im = of_re + 1024;
  float* bvar  = of_im + 1024;

  float* out0f = (float*)d_out;                       // 4096x1024 f32 (real)
  float* out1f = out0f + (size_t)4096 * 1024;         // 16x1024 f32 (real)

  // --- Cayley via Newton-Schulz (||A|| <= 0.4 by construction) --------------
  build_gx_k<<<4096, TPB, 0, stream>>>(v_raw_re, v_raw_im, Gr, Gi, Pr, Pi);
  float *Xr = Pr, *Xi = Pi, *Zr = Qr, *Zi = Qi;
  for (int it = 0; it < 3; ++it) {                 // residual -> ||A||^16 ~ 4e-7
    cgemm_k<<<dim3(16, 16), TPB, 0, stream>>>(Gr, Gi, Xr, Xi, Yr, Yi, 1);  // Y = 2I - G@X
    cgemm_k<<<dim3(16, 16), TPB, 0, stream>>>(Xr, Xi, Yr, Yi, Zr, Zi, 0);  // X' = X@Y
    float* t;
    t = Xr; Xr = Zr; Zr = t;
    t = Xi; Xi = Zi; Zi = t;
  }
  // V = X@(I-A) = 2X - X@G   (X ends in Q planes after 3 iters)
  cgemm_k<<<dim3(16, 16), TPB, 0, stream>>>(Xr, Xi, Gr, Gi, Vr, Vi, 2);
  build_m_k<<<4096, TPB, 0, stream>>>(Vr, Vi, log_sigma, dft_weight, Mr, Mi);

  // --- per-d constants + flux/source/gate chain (B=16 rows) -----------------
  prep_k<<<4, TPB, 0, stream>>>(ld, lf, law_re, law_im, dt, base_noise,
                                od_re, od_im, of_re, of_im, bvar);
  small_gemm_k<<<dim3(8, 4), TPB, 0, stream>>>(xg_re, xg_im, Wi_in, bi, xin, 2048, 0);
  flux_k<<<64, TPB, 0, stream>>>(xin, flux_re, flux_im, decay_re, decay_im,
                                 FNr, FNi, out1f);
  small_gemm_k<<<dim3(8, 4), TPB, 0, stream>>>(FNr, FNi, Wo, bo, proj, 2048, 0);
  small_gemm_k<<<dim3(4, 4), TPB, 0, stream>>>(FNr, FNi, Wg, bg, gate, 1024, 1);

  // --- x_tilde = x@M fused with h_next epilogue -> Hr (overwrites planes 2..5)
  xmh_k<<<dim3(16, 64), TPB, 0, stream>>>(x_input, Mr, Mi, gate, proj,
                                          od_re, od_im, of_re, of_im,
                                          h_prev_re, h_prev_im, Hr);

  // --- u-MLP + final noisy output (f32, real part) --------------------------
  mlp1_k<<<dim3(4, 64), TPB, 0, stream>>>(Hr, Wu1, bu1, mlp1);
  final_k<<<dim3(16, 64), TPB, 0, stream>>>(mlp1, Wu2, bu2, Hr,
                                            noise_re, bvar, out0f);
}

// Round 6
// 606.737 us; speedup vs baseline: 4.2346x; 4.2346x over previous
//
#include <hip/hip_runtime.h>
#include <cstddef>

#define TPB 256

typedef short bf8v  __attribute__((ext_vector_type(8)));   // 8 bf16 bit-patterns
typedef float f32x4 __attribute__((ext_vector_type(4)));

#define LSTR 40      // LDS row stride in ushorts (80B: 16B-aligned, 2-way banks)
#define PLSTR 2560   // 64*LSTR
#define BUF4 10240   // 4 planes (cgemm)
#define BUF3 7680    // 3 planes (xmh)

static __device__ __forceinline__ unsigned short f2bf(float x) {
  unsigned int u = __float_as_uint(x);
  u = (u + 0x7FFFu + ((u >> 16) & 1u)) >> 16;   // RNE f32 -> bf16
  return (unsigned short)u;
}
static __device__ __forceinline__ float sigmoidf_(float x) {
  return 1.0f / (1.0f + expf(-x));
}
static __device__ __forceinline__ bf8v neg8(bf8v a) {
  #pragma unroll
  for (int i = 0; i < 8; ++i) a[i] ^= (short)0x8000;
  return a;
}
static __device__ __forceinline__ void pack8(const float4& x, const float4& y,
                                             unsigned short* dst) {
  unsigned int* d = (unsigned int*)dst;
  d[0] = ((unsigned)f2bf(x.y) << 16) | f2bf(x.x);
  d[1] = ((unsigned)f2bf(x.w) << 16) | f2bf(x.z);
  d[2] = ((unsigned)f2bf(y.y) << 16) | f2bf(y.x);
  d[3] = ((unsigned)f2bf(y.w) << 16) | f2bf(y.z);
}

// ---------------------------------------------------------------------------
// build G = I + A and X0 = I - A, where A = (v - v^T)re + i(v + v^T)im
// ---------------------------------------------------------------------------
__global__ __launch_bounds__(TPB) void build_gx_k(
    const float* __restrict__ vre, const float* __restrict__ vim,
    float* __restrict__ Gr, float* __restrict__ Gi,
    float* __restrict__ Xr, float* __restrict__ Xi)
{
  int idx = blockIdx.x * TPB + threadIdx.x;
  int i = idx >> 10, j = idx & 1023;
  float ar = vre[idx] - vre[j * 1024 + i];
  float ai = vim[idx] + vim[j * 1024 + i];
  float dg = (i == j) ? 1.0f : 0.0f;
  Gr[idx] = dg + ar;  Gi[idx] = ai;
  Xr[idx] = dg - ar;  Xi[idx] = -ai;
}

// ---------------------------------------------------------------------------
// complex GEMM (1024^3, NN) on MFMA: mode 0: C = A@B
//                                    mode 1: C = 2I - A@B
//                                    mode 2: C = 2A - A@B
// 64x64 tile, 4 waves (2x2 quadrants of 32x32), bf16 inputs / f32 accum.
// ---------------------------------------------------------------------------
__global__ __launch_bounds__(TPB) void cgemm_mfma_k(
    const float* __restrict__ Apr, const float* __restrict__ Api,
    const float* __restrict__ Bpr, const float* __restrict__ Bpi,
    float* __restrict__ Cr, float* __restrict__ Ci, int mode)
{
  __shared__ __align__(16) unsigned short lds[2 * BUF4];
  int tid = threadIdx.x;
  int bm = blockIdx.y * 64, bn = blockIdx.x * 64;
  int lane = tid & 63;
  int wr = (tid >> 7) & 1, wc = (tid >> 6) & 1;
  int arow = tid >> 2, akq = (tid & 3) << 3;        // A stage: 64 rows x 32k
  int bnl = tid & 63, bk2 = (tid >> 6) << 1;        // B stage: transpose pairs

  f32x4 accR[2][2] = {};
  f32x4 accI[2][2] = {};
  float4 pa[2][2];
  float  pb[2][8];

  auto gload = [&](int k0) {
    const float* p0 = Apr + (size_t)(bm + arow) * 1024 + k0 + akq;
    const float* p1 = Api + (size_t)(bm + arow) * 1024 + k0 + akq;
    pa[0][0] = *(const float4*)p0; pa[0][1] = *(const float4*)(p0 + 4);
    pa[1][0] = *(const float4*)p1; pa[1][1] = *(const float4*)(p1 + 4);
    #pragma unroll
    for (int i = 0; i < 4; ++i) {
      size_t r0 = (size_t)(k0 + i * 8 + bk2) * 1024 + bn + bnl;
      pb[0][2*i]   = Bpr[r0];  pb[0][2*i+1] = Bpr[r0 + 1024];
      pb[1][2*i]   = Bpi[r0];  pb[1][2*i+1] = Bpi[r0 + 1024];
    }
  };
  auto stolds = [&](int buf) {
    unsigned short* L = lds + buf * BUF4;
    pack8(pa[0][0], pa[0][1], L + 0 * PLSTR + arow * LSTR + akq);
    pack8(pa[1][0], pa[1][1], L + 1 * PLSTR + arow * LSTR + akq);
    #pragma unroll
    for (int i = 0; i < 4; ++i) {
      unsigned int w0 = ((unsigned)f2bf(pb[0][2*i+1]) << 16) | f2bf(pb[0][2*i]);
      unsigned int w1 = ((unsigned)f2bf(pb[1][2*i+1]) << 16) | f2bf(pb[1][2*i]);
      *(unsigned int*)&L[2 * PLSTR + bnl * LSTR + i * 8 + bk2] = w0;
      *(unsigned int*)&L[3 * PLSTR + bnl * LSTR + i * 8 + bk2] = w1;
    }
  };
  auto compute = [&](int buf) {
    const unsigned short* L = lds + buf * BUF4;
    int r0 = (wr * 32 + (lane & 15)) * LSTR + (lane >> 4) * 8;
    int c0 = (wc * 32 + (lane & 15)) * LSTR + (lane >> 4) * 8;
    bf8v ar[2], ai[2], br[2], bi[2];
    ar[0] = *(const bf8v*)(L + 0 * PLSTR + r0);
    ar[1] = *(const bf8v*)(L + 0 * PLSTR + r0 + 16 * LSTR);
    ai[0] = *(const bf8v*)(L + 1 * PLSTR + r0);
    ai[1] = *(const bf8v*)(L + 1 * PLSTR + r0 + 16 * LSTR);
    br[0] = *(const bf8v*)(L + 2 * PLSTR + c0);
    br[1] = *(const bf8v*)(L + 2 * PLSTR + c0 + 16 * LSTR);
    bi[0] = *(const bf8v*)(L + 3 * PLSTR + c0);
    bi[1] = *(const bf8v*)(L + 3 * PLSTR + c0 + 16 * LSTR);
    bf8v an[2] = { neg8(ai[0]), neg8(ai[1]) };
    #pragma unroll
    for (int mf = 0; mf < 2; ++mf)
      #pragma unroll
      for (int nf = 0; nf < 2; ++nf) {
        accR[mf][nf] = __builtin_amdgcn_mfma_f32_16x16x32_bf16(ar[mf], br[nf], accR[mf][nf], 0, 0, 0);
        accR[mf][nf] = __builtin_amdgcn_mfma_f32_16x16x32_bf16(an[mf], bi[nf], accR[mf][nf], 0, 0, 0);
        accI[mf][nf] = __builtin_amdgcn_mfma_f32_16x16x32_bf16(ar[mf], bi[nf], accI[mf][nf], 0, 0, 0);
        accI[mf][nf] = __builtin_amdgcn_mfma_f32_16x16x32_bf16(ai[mf], br[nf], accI[mf][nf], 0, 0, 0);
      }
  };

  gload(0); stolds(0); __syncthreads();
  int cur = 0;
  for (int t = 0; t < 32; ++t) {
    if (t < 31) gload((t + 1) * 32);
    compute(cur);
    if (t < 31) stolds(cur ^ 1);
    __syncthreads();
    cur ^= 1;
  }

  #pragma unroll
  for (int mf = 0; mf < 2; ++mf)
    #pragma unroll
    for (int nf = 0; nf < 2; ++nf) {
      int col = bn + wc * 32 + nf * 16 + (lane & 15);
      #pragma unroll
      for (int r = 0; r < 4; ++r) {
        int row = bm + wr * 32 + mf * 16 + (lane >> 4) * 4 + r;
        float vr = accR[mf][nf][r], vi = accI[mf][nf][r];
        if (mode == 1) { vr = ((row == col) ? 2.0f : 0.0f) - vr; vi = -vi; }
        if (mode == 2) {
          size_t o = (size_t)row * 1024 + col;
          vr = 2.0f * Apr[o] - vr;  vi = 2.0f * Api[o] - vi;
        }
        Cr[(size_t)row * 1024 + col] = vr;
        Ci[(size_t)row * 1024 + col] = vi;
      }
    }
}

// ---------------------------------------------------------------------------
// M = V*diag(exp(log_sigma))*(1-alpha) + F*alpha   (F = DFT basis / 32)
// ---------------------------------------------------------------------------
__global__ __launch_bounds__(TPB) void build_m_k(
    const float* __restrict__ Vr, const float* __restrict__ Vi,
    const float* __restrict__ log_sigma, const float* __restrict__ dft_weight,
    float* __restrict__ Mr, float* __restrict__ Mi)
{
  int idx = blockIdx.x * TPB + threadIdx.x;
  int k = idx >> 10, dp = idx & 1023;
  float alpha = sigmoidf_(dft_weight[0]);
  float w1 = expf(log_sigma[dp]) * (1.0f - alpha);
  int mm = (k * dp) & 1023;                       // exact angle reduction
  float ang = -6.283185307179586f * (float)mm * (1.0f / 1024.0f);
  float sn, cs;
  sincosf(ang, &sn, &cs);
  const float isq = 0.03125f * alpha;             // alpha / sqrt(1024)
  Mr[idx] = Vr[idx] * w1 + cs * isq;
  Mi[idx] = Vi[idx] * w1 + sn * isq;
}

// ---------------------------------------------------------------------------
// per-d constants: op_decay, op_forcing, base_var
// ---------------------------------------------------------------------------
__global__ __launch_bounds__(TPB) void prep_k(
    const float* __restrict__ ld, const float* __restrict__ lf,
    const float* __restrict__ law_re, const float* __restrict__ law_im,
    const float* __restrict__ dt, const float* __restrict__ base_noise,
    float* __restrict__ od_re, float* __restrict__ od_im,
    float* __restrict__ of_re, float* __restrict__ of_im,
    float* __restrict__ bvar)
{
  int d = blockIdx.x * TPB + threadIdx.x;
  float dtr = dt[0];                              // DT_REF = 1.0
  float lre = tanhf(-expf(ld[d]) + law_re[d]) * 0.3f;
  float lim = lf[d] + law_im[d];
  float er = expf(lre * dtr);
  float sn, cs;
  sincosf(lim * dtr, &sn, &cs);
  float odr = er * cs, odi = er * sn;
  od_re[d] = odr;  od_im[d] = odi;
  float numr = odr - 1.0f, numi = odi;
  float denr = lre + 1e-8f, deni = lim;
  float inv = 1.0f / (denr * denr + deni * deni);
  of_re[d] = (numr * denr + numi * deni) * inv;
  of_im[d] = (numi * denr - numr * deni) * inv;
  float bn = base_noise[0];
  float bv = bn * bn * expm1f(2.0f * lre * dtr) / (2.0f * lre + 1e-8f);
  bvar[d] = fmaxf(bv, 0.0f);
}

// ---------------------------------------------------------------------------
// small (16 x N) gemm: C[r,c] = sum_k [A0|A1][r,k] * Bw[c,k] + bias[c]
// ---------------------------------------------------------------------------
__global__ __launch_bounds__(TPB) void small_gemm_k(
    const float* __restrict__ A0, const float* __restrict__ A1,
    const float* __restrict__ Bw, const float* __restrict__ bias,
    float* __restrict__ C, int N, int act)
{
  int c = blockIdx.x * TPB + threadIdx.x;
  int r0 = blockIdx.y * 4;
  float acc[4] = {0.0f, 0.0f, 0.0f, 0.0f};
  const float* brow = Bw + (size_t)c * 2048;
  for (int k = 0; k < 1024; k += 4) {
    float4 b0 = *(const float4*)(brow + k);
    float4 b1 = *(const float4*)(brow + 1024 + k);
    #pragma unroll
    for (int r = 0; r < 4; ++r) {
      const float* a0 = A0 + (size_t)(r0 + r) * 1024 + k;
      const float* a1 = A1 + (size_t)(r0 + r) * 1024 + k;
      acc[r] += a0[0] * b0.x + a0[1] * b0.y + a0[2] * b0.z + a0[3] * b0.w
              + a1[0] * b1.x + a1[1] * b1.y + a1[2] * b1.z + a1[3] * b1.w;
    }
  }
  #pragma unroll
  for (int r = 0; r < 4; ++r) {
    float v = acc[r] + bias[c];
    if (act == 1) v = sigmoidf_(v);
    C[(size_t)(r0 + r) * N + c] = v;
  }
}

// ---------------------------------------------------------------------------
// flux_next = flux*fdecay + update ; FN planes + f32 output 1 = Re(flux_next)
// ---------------------------------------------------------------------------
__global__ __launch_bounds__(TPB) void flux_k(
    const float* __restrict__ xin,
    const float* __restrict__ flux_re, const float* __restrict__ flux_im,
    const float* __restrict__ decay_re, const float* __restrict__ decay_im,
    float* __restrict__ FNr, float* __restrict__ FNi,
    float* __restrict__ out1)
{
  int idx = blockIdx.x * TPB + threadIdx.x;     // 16 * 1024
  int b = idx >> 10, d = idx & 1023;
  float fdr = sigmoidf_(decay_re[d]);
  float fdi = decay_im[d];
  float fr = flux_re[idx], fi = flux_im[idx];
  float ur = xin[b * 2048 + d], ui = xin[b * 2048 + 1024 + d];
  float nr = fr * fdr - fi * fdi + ur;
  float ni = fr * fdi + fi * fdr + ui;
  FNr[idx] = nr;  FNi[idx] = ni;
  out1[idx] = nr;                                // f32, real part only
}

// ---------------------------------------------------------------------------
// fused MFMA: x_tilde = x @ M (real A, complex B) + h_next epilogue -> Hr
// ---------------------------------------------------------------------------
__global__ __launch_bounds__(TPB) void xmh_mfma_k(
    const float* __restrict__ Xin,
    const float* __restrict__ Mr, const float* __restrict__ Mi,
    const float* __restrict__ gate, const float* __restrict__ proj,
    const float* __restrict__ od_re, const float* __restrict__ od_im,
    const float* __restrict__ of_re, const float* __restrict__ of_im,
    const float* __restrict__ hp_re, const float* __restrict__ hp_im,
    float* __restrict__ Hr)
{
  __shared__ __align__(16) unsigned short lds[2 * BUF3];
  int tid = threadIdx.x;
  int bm = blockIdx.y * 64, bn = blockIdx.x * 64;
  int lane = tid & 63;
  int wr = (tid >> 7) & 1, wc = (tid >> 6) & 1;
  int arow = tid >> 2, akq = (tid & 3) << 3;
  int bnl = tid & 63, bk2 = (tid >> 6) << 1;

  f32x4 accR[2][2] = {};
  f32x4 accI[2][2] = {};
  float4 pa[2];
  float  pb[2][8];

  auto gload = [&](int k0) {
    const float* p0 = Xin + (size_t)(bm + arow) * 1024 + k0 + akq;
    pa[0] = *(const float4*)p0; pa[1] = *(const float4*)(p0 + 4);
    #pragma unroll
    for (int i = 0; i < 4; ++i) {
      size_t r0 = (size_t)(k0 + i * 8 + bk2) * 1024 + bn + bnl;
      pb[0][2*i]   = Mr[r0];  pb[0][2*i+1] = Mr[r0 + 1024];
      pb[1][2*i]   = Mi[r0];  pb[1][2*i+1] = Mi[r0 + 1024];
    }
  };
  auto stolds = [&](int buf) {
    unsigned short* L = lds + buf * BUF3;
    pack8(pa[0], pa[1], L + 0 * PLSTR + arow * LSTR + akq);
    #pragma unroll
    for (int i = 0; i < 4; ++i) {
      unsigned int w0 = ((unsigned)f2bf(pb[0][2*i+1]) << 16) | f2bf(pb[0][2*i]);
      unsigned int w1 = ((unsigned)f2bf(pb[1][2*i+1]) << 16) | f2bf(pb[1][2*i]);
      *(unsigned int*)&L[1 * PLSTR + bnl * LSTR + i * 8 + bk2] = w0;
      *(unsigned int*)&L[2 * PLSTR + bnl * LSTR + i * 8 + bk2] = w1;
    }
  };
  auto compute = [&](int buf) {
    const unsigned short* L = lds + buf * BUF3;
    int r0 = (wr * 32 + (lane & 15)) * LSTR + (lane >> 4) * 8;
    int c0 = (wc * 32 + (lane & 15)) * LSTR + (lane >> 4) * 8;
    bf8v a[2], br[2], bi[2];
    a[0]  = *(const bf8v*)(L + 0 * PLSTR + r0);
    a[1]  = *(const bf8v*)(L + 0 * PLSTR + r0 + 16 * LSTR);
    br[0] = *(const bf8v*)(L + 1 * PLSTR + c0);
    br[1] = *(const bf8v*)(L + 1 * PLSTR + c0 + 16 * LSTR);
    bi[0] = *(const bf8v*)(L + 2 * PLSTR + c0);
    bi[1] = *(const bf8v*)(L + 2 * PLSTR + c0 + 16 * LSTR);
    #pragma unroll
    for (int mf = 0; mf < 2; ++mf)
      #pragma unroll
      for (int nf = 0; nf < 2; ++nf) {
        accR[mf][nf] = __builtin_amdgcn_mfma_f32_16x16x32_bf16(a[mf], br[nf], accR[mf][nf], 0, 0, 0);
        accI[mf][nf] = __builtin_amdgcn_mfma_f32_16x16x32_bf16(a[mf], bi[nf], accI[mf][nf], 0, 0, 0);
      }
  };

  gload(0); stolds(0); __syncthreads();
  int cur = 0;
  for (int t = 0; t < 32; ++t) {
    if (t < 31) gload((t + 1) * 32);
    compute(cur);
    if (t < 31) stolds(cur ^ 1);
    __syncthreads();
    cur ^= 1;
  }

  #pragma unroll
  for (int mf = 0; mf < 2; ++mf)
    #pragma unroll
    for (int nf = 0; nf < 2; ++nf) {
      int c = bn + wc * 32 + nf * 16 + (lane & 15);
      #pragma unroll
      for (int r = 0; r < 4; ++r) {
        int t = bm + wr * 32 + mf * 16 + (lane >> 4) * 4 + r;
        int b = t >> 8;
        float g  = gate[b * 1024 + c];
        float sr = proj[b * 2048 + c];
        float si = proj[b * 2048 + 1024 + c];
        float fr = accR[mf][nf][r] * g + sr * (1.0f - g);
        float fi = accI[mf][nf][r] * g + si * (1.0f - g);
        float odr = od_re[c], odi = od_im[c];
        float ofr = of_re[c], ofi = of_im[c];
        size_t off = (size_t)t * 1024 + c;
        float pr = hp_re[off], pi = hp_im[off];
        Hr[off] = pr * odr - pi * odi + fr * ofr - fi * ofi;   // real part only
      }
    }
}

// ---------------------------------------------------------------------------
// mlp1 = silu(Hr @ Wu1^T + bu1)    (4096x1024 @ 1024x256)
// ---------------------------------------------------------------------------
__global__ __launch_bounds__(TPB) void mlp1_k(
    const float* __restrict__ A, const float* __restrict__ Bw,
    const float* __restrict__ bias, float* __restrict__ C)
{
  __shared__ float As[64][17], Bs[64][17];
  int tid = threadIdx.x;
  int tx = tid & 15, ty = tid >> 4;
  int bm = blockIdx.y * 64, bn = blockIdx.x * 64;
  float acc[4][4] = {{0.0f}};
  int lr = tid >> 2, lkq = (tid & 3) << 2;
  for (int k0 = 0; k0 < 1024; k0 += 16) {
    float4 a0 = *(const float4*)(A  + (size_t)(bm + lr) * 1024 + k0 + lkq);
    float4 b0 = *(const float4*)(Bw + (size_t)(bn + lr) * 1024 + k0 + lkq);
    As[lr][lkq] = a0.x; As[lr][lkq + 1] = a0.y; As[lr][lkq + 2] = a0.z; As[lr][lkq + 3] = a0.w;
    Bs[lr][lkq] = b0.x; Bs[lr][lkq + 1] = b0.y; Bs[lr][lkq + 2] = b0.z; Bs[lr][lkq + 3] = b0.w;
    __syncthreads();
    #pragma unroll
    for (int kk = 0; kk < 16; ++kk) {
      float a4[4], b4[4];
      #pragma unroll
      for (int m = 0; m < 4; ++m) a4[m] = As[ty + 16 * m][kk];
      #pragma unroll
      for (int n = 0; n < 4; ++n) b4[n] = Bs[tx + 16 * n][kk];
      #pragma unroll
      for (int m = 0; m < 4; ++m) {
        #pragma unroll
        for (int n = 0; n < 4; ++n) acc[m][n] += a4[m] * b4[n];
      }
    }
    __syncthreads();
  }
  #pragma unroll
  for (int m = 0; m < 4; ++m) {
    int t = bm + ty + 16 * m;
    #pragma unroll
    for (int n = 0; n < 4; ++n) {
      int c = bn + tx + 16 * n;
      float v = acc[m][n] + bias[c];
      v = v * sigmoidf_(v);                       // silu
      C[(size_t)t * 256 + c] = v;
    }
  }
}

// ---------------------------------------------------------------------------
// u = softplus(mlp1 @ Wu2^T + bu2); out0 = f32(Re(h) + noise_re*std)
// ---------------------------------------------------------------------------
__global__ __launch_bounds__(TPB) void final_k(
    const float* __restrict__ A, const float* __restrict__ Bw,
    const float* __restrict__ bias,
    const float* __restrict__ Hr,
    const float* __restrict__ nre,
    const float* __restrict__ bvar,
    float* __restrict__ out0)
{
  __shared__ float As[64][17], Bs[64][17];
  int tid = threadIdx.x;
  int tx = tid & 15, ty = tid >> 4;
  int bm = blockIdx.y * 64, bn = blockIdx.x * 64;
  float acc[4][4] = {{0.0f}};
  int lr = tid >> 2, lkq = (tid & 3) << 2;
  for (int k0 = 0; k0 < 256; k0 += 16) {
    float4 a0 = *(const float4*)(A  + (size_t)(bm + lr) * 256 + k0 + lkq);
    float4 b0 = *(const float4*)(Bw + (size_t)(bn + lr) * 256 + k0 + lkq);
    As[lr][lkq] = a0.x; As[lr][lkq + 1] = a0.y; As[lr][lkq + 2] = a0.z; As[lr][lkq + 3] = a0.w;
    Bs[lr][lkq] = b0.x; Bs[lr][lkq + 1] = b0.y; Bs[lr][lkq + 2] = b0.z; Bs[lr][lkq + 3] = b0.w;
    __syncthreads();
    #pragma unroll
    for (int kk = 0; kk < 16; ++kk) {
      float a4[4], b4[4];
      #pragma unroll
      for (int m = 0; m < 4; ++m) a4[m] = As[ty + 16 * m][kk];
      #pragma unroll
      for (int n = 0; n < 4; ++n) b4[n] = Bs[tx + 16 * n][kk];
      #pragma unroll
      for (int m = 0; m < 4; ++m) {
        #pragma unroll
        for (int n = 0; n < 4; ++n) acc[m][n] += a4[m] * b4[n];
      }
    }
    __syncthreads();
  }
  #pragma unroll
  for (int m = 0; m < 4; ++m) {
    int t = bm + ty + 16 * m;
    #pragma unroll
    for (int n = 0; n < 4; ++n) {
      int c = bn + tx + 16 * n;
      float v = acc[m][n] + bias[c];
      float u = (v > 20.0f) ? v : log1pf(expf(v));    // softplus
      float sc = sqrtf(bvar[c] * u) * 0.7071067811865476f;
      size_t off = (size_t)t * 1024 + c;
      out0[off] = Hr[off] + nre[off] * sc;            // f32, real part only
    }
  }
}

// ---------------------------------------------------------------------------
extern "C" void kernel_launch(void* const* d_in, const int* in_sizes, int n_in,
                              void* d_out, int out_size, void* d_ws, size_t ws_size,
                              hipStream_t stream) {
  (void)in_sizes; (void)n_in; (void)out_size;

  const float* x_input    = (const float*)d_in[0];
  const float* h_prev_re  = (const float*)d_in[1];
  const float* h_prev_im  = (const float*)d_in[2];
  const float* xg_re      = (const float*)d_in[3];
  const float* xg_im      = (const float*)d_in[4];
  const float* flux_re    = (const float*)d_in[5];
  const float* flux_im    = (const float*)d_in[6];
  const float* dt         = (const float*)d_in[7];
  const float* v_raw_re   = (const float*)d_in[10];
  const float* v_raw_im   = (const float*)d_in[11];
  const float* log_sigma  = (const float*)d_in[12];
  const float* dft_weight = (const float*)d_in[13];
  const float* decay_re   = (const float*)d_in[14];
  const float* decay_im   = (const float*)d_in[15];
  const float* Wi_in      = (const float*)d_in[16];
  const float* bi         = (const float*)d_in[17];
  const float* Wo         = (const float*)d_in[18];
  const float* bo         = (const float*)d_in[19];
  const float* Wg         = (const float*)d_in[20];
  const float* bg         = (const float*)d_in[21];
  const float* ld         = (const float*)d_in[22];
  const float* lf         = (const float*)d_in[23];
  const float* law_re     = (const float*)d_in[24];
  const float* law_im     = (const float*)d_in[25];
  const float* base_noise = (const float*)d_in[26];
  const float* Wu1        = (const float*)d_in[27];
  const float* bu1        = (const float*)d_in[28];
  const float* Wu2        = (const float*)d_in[29];
  const float* bu2        = (const float*)d_in[30];
  const float* noise_re   = (const float*)d_in[31];

  // --- workspace: 10 planes of 1M floats + smalls ---------------------------
  const size_t PL = 1024ull * 1024ull;
  const size_t SMALL = 2 * 32768 + 3 * 16384 + 5 * 1024;
  if (ws_size < (10 * PL + SMALL) * 4) return;  // too small -> zeros (diagnostic)

  float* w = (float*)d_ws;
  float* Gr = w + 0 * PL;  float* Gi = w + 1 * PL;   // G; -> M after Newton
  float* Pr = w + 2 * PL;  float* Pi = w + 3 * PL;   // X ping
  float* Qr = w + 4 * PL;  float* Qi = w + 5 * PL;   // X pong
  float* Yr = w + 6 * PL;  float* Yi = w + 7 * PL;   // Newton temp
  float* Vr = w + 8 * PL;  float* Vi = w + 9 * PL;   // V result
  float* Mr = Gr;          float* Mi = Gi;           // M overwrites G
  float* Hr = w + 2 * PL;                            // 4 planes (P,Q dead)
  float* mlp1 = w + 6 * PL;                          // 1 plane (Y dead)
  float* xin  = w + 10 * PL;            // 16x2048
  float* proj = xin + 32768;            // 16x2048
  float* FNr  = proj + 32768;           // 16x1024
  float* FNi  = FNr + 16384;
  float* gate = FNi + 16384;            // 16x1024
  float* od_re = gate + 16384;
  float* od_im = od_re + 1024;
  float* of_re = od_im + 1024;
  float* of_im = of_re + 1024;
  float* bvar  = of_im + 1024;

  float* out0f = (float*)d_out;                       // 4096x1024 f32 (real)
  float* out1f = out0f + (size_t)4096 * 1024;         // 16x1024 f32 (real)

  // --- Cayley via Newton-Schulz (||A|| <= 0.4; R0 = A^2, 2 iters -> 6.5e-4) -
  build_gx_k<<<4096, TPB, 0, stream>>>(v_raw_re, v_raw_im, Gr, Gi, Pr, Pi);
  float *Xr = Pr, *Xi = Pi, *Zr = Qr, *Zi = Qi;
  for (int it = 0; it < 2; ++it) {
    cgemm_mfma_k<<<dim3(16, 16), TPB, 0, stream>>>(Gr, Gi, Xr, Xi, Yr, Yi, 1);  // Y = 2I - G@X
    cgemm_mfma_k<<<dim3(16, 16), TPB, 0, stream>>>(Xr, Xi, Yr, Yi, Zr, Zi, 0);  // X' = X@Y
    float* t;
    t = Xr; Xr = Zr; Zr = t;
    t = Xi; Xi = Zi; Zi = t;
  }
  // V = X@(I-A) = 2X - X@G   (X ends in P planes after 2 iters)
  cgemm_mfma_k<<<dim3(16, 16), TPB, 0, stream>>>(Xr, Xi, Gr, Gi, Vr, Vi, 2);
  build_m_k<<<4096, TPB, 0, stream>>>(Vr, Vi, log_sigma, dft_weight, Mr, Mi);

  // --- per-d constants + flux/source/gate chain (B=16 rows) -----------------
  prep_k<<<4, TPB, 0, stream>>>(ld, lf, law_re, law_im, dt, base_noise,
                                od_re, od_im, of_re, of_im, bvar);
  small_gemm_k<<<dim3(8, 4), TPB, 0, stream>>>(xg_re, xg_im, Wi_in, bi, xin, 2048, 0);
  flux_k<<<64, TPB, 0, stream>>>(xin, flux_re, flux_im, decay_re, decay_im,
                                 FNr, FNi, out1f);
  small_gemm_k<<<dim3(8, 4), TPB, 0, stream>>>(FNr, FNi, Wo, bo, proj, 2048, 0);
  small_gemm_k<<<dim3(4, 4), TPB, 0, stream>>>(FNr, FNi, Wg, bg, gate, 1024, 1);

  // --- x_tilde = x@M (MFMA) fused with h_next epilogue -> Hr ----------------
  xmh_mfma_k<<<dim3(16, 64), TPB, 0, stream>>>(x_input, Mr, Mi, gate, proj,
                                               od_re, od_im, of_re, of_im,
                                               h_prev_re, h_prev_im, Hr);

  // --- u-MLP + final noisy output (f32, real part) --------------------------
  mlp1_k<<<dim3(4, 64), TPB, 0, stream>>>(Hr, Wu1, bu1, mlp1);
  final_k<<<dim3(16, 64), TPB, 0, stream>>>(mlp1, Wu2, bu2, Hr,
                                            noise_re, bvar, out0f);
}

// Round 7
// 428.159 us; speedup vs baseline: 6.0008x; 1.4171x over previous
//
#include <hip/hip_runtime.h>
#include <cstddef>

#define TPB 256

typedef short bf8v  __attribute__((ext_vector_type(8)));   // 8 bf16 bit-patterns
typedef float f32x4 __attribute__((ext_vector_type(4)));
typedef unsigned short u16;

#define LSTR 40      // LDS row stride in u16 (80B: 16B-aligned, 2-way banks)
#define PLSTR 2560   // 64*LSTR
#define BUF4 10240   // 4 planes (complex NT gemm)
#define BUF3 7680    // 3 planes (xmh)
#define BUF2 5120    // 2 planes (real NT gemm)

static __device__ __forceinline__ u16 f2bf(float x) {
  unsigned int u = __float_as_uint(x);
  u = (u + 0x7FFFu + ((u >> 16) & 1u)) >> 16;   // RNE f32 -> bf16
  return (u16)u;
}
static __device__ __forceinline__ float bf2f(u16 x) {
  return __uint_as_float(((unsigned int)x) << 16);
}
static __device__ __forceinline__ float sigmoidf_(float x) {
  return 1.0f / (1.0f + expf(-x));
}
static __device__ __forceinline__ bf8v neg8(bf8v a) {
  #pragma unroll
  for (int i = 0; i < 8; ++i) a[i] ^= (short)0x8000;
  return a;
}
static __device__ __forceinline__ void pack8(const float4& x, const float4& y,
                                             u16* dst) {
  unsigned int* d = (unsigned int*)dst;
  d[0] = ((unsigned)f2bf(x.y) << 16) | f2bf(x.x);
  d[1] = ((unsigned)f2bf(x.w) << 16) | f2bf(x.z);
  d[2] = ((unsigned)f2bf(y.y) << 16) | f2bf(y.x);
  d[3] = ((unsigned)f2bf(y.w) << 16) | f2bf(y.z);
}

// ---------------------------------------------------------------------------
// A = (v - v^T)re + i(v + v^T)im  -> bf16 planes.  (Ar antisym, Ai sym)
// ---------------------------------------------------------------------------
__global__ __launch_bounds__(TPB) void build_a_k(
    const float* __restrict__ vre, const float* __restrict__ vim,
    u16* __restrict__ Ar, u16* __restrict__ Ai)
{
  int idx = blockIdx.x * TPB + threadIdx.x;
  int i = idx >> 10, j = idx & 1023;
  Ar[idx] = f2bf(vre[idx] - vre[j * 1024 + i]);
  Ai[idx] = f2bf(vim[idx] + vim[j * 1024 + i]);
}

// ---------------------------------------------------------------------------
// q1 = I - 2A + 2A^2 - 2A^3 ; q2 = q1 + I   (bf16 in/out)
// ---------------------------------------------------------------------------
__global__ __launch_bounds__(TPB) void build_q_k(
    const u16* __restrict__ Ar, const u16* __restrict__ Ai,
    const u16* __restrict__ A2r, const u16* __restrict__ A2i,
    const u16* __restrict__ A3r, const u16* __restrict__ A3i,
    u16* __restrict__ q1r, u16* __restrict__ q1i,
    u16* __restrict__ q2r, u16* __restrict__ q2i)
{
  int idx = blockIdx.x * TPB + threadIdx.x;
  int i = idx >> 10, j = idx & 1023;
  float dg = (i == j) ? 1.0f : 0.0f;
  float r = dg - 2.0f * bf2f(Ar[idx]) + 2.0f * bf2f(A2r[idx]) - 2.0f * bf2f(A3r[idx]);
  float m = -2.0f * bf2f(Ai[idx]) + 2.0f * bf2f(A2i[idx]) - 2.0f * bf2f(A3i[idx]);
  q1r[idx] = f2bf(r);      q1i[idx] = f2bf(m);
  q2r[idx] = f2bf(r + dg); q2i[idx] = f2bf(m);
}

// ---------------------------------------------------------------------------
// complex NT GEMM (1024^3), bf16: C = A@B_true.
// Both operands staged as ROWS [64][32] (contiguous in k).  B_true relates to
// the stored B-plane rows b^ by symmetry:
//   BNEG=0 (B-plane = A itself):  B_true = (-b^r, +b^i)   [A^T = -conj(A)]
//   BNEG=1 (B-plane = A^{2k}):    B_true = (+b^r, -b^i)   [(A^2k)^T = conj]
// EPI=0: store bf16.  EPI=1: C += q1 (bf16 reload), store f32.
// ---------------------------------------------------------------------------
template<int BNEG, int EPI>
__global__ __launch_bounds__(TPB) void cgemm_nt_k(
    const u16* __restrict__ Apr, const u16* __restrict__ Api,
    const u16* __restrict__ Bpr, const u16* __restrict__ Bpi,
    u16* __restrict__ Cr16, u16* __restrict__ Ci16,
    const u16* __restrict__ q1r, const u16* __restrict__ q1i,
    float* __restrict__ Crf, float* __restrict__ Cif)
{
  __shared__ __align__(16) u16 lds[2 * BUF4];
  int tid = threadIdx.x;
  int bm = blockIdx.y * 64, bn = blockIdx.x * 64;
  int lane = tid & 63;
  int wr = (tid >> 7) & 1, wc = (tid >> 6) & 1;
  int row = tid >> 2, ch = (tid & 3) << 3;

  f32x4 accR[2][2] = {};
  f32x4 accI[2][2] = {};
  bf8v pa[4];

  auto gload = [&](int k0) {
    pa[0] = *(const bf8v*)(Apr + (size_t)(bm + row) * 1024 + k0 + ch);
    pa[1] = *(const bf8v*)(Api + (size_t)(bm + row) * 1024 + k0 + ch);
    pa[2] = *(const bf8v*)(Bpr + (size_t)(bn + row) * 1024 + k0 + ch);
    pa[3] = *(const bf8v*)(Bpi + (size_t)(bn + row) * 1024 + k0 + ch);
  };
  auto stolds = [&](int buf) {
    u16* L = lds + buf * BUF4 + row * LSTR + ch;
    *(bf8v*)(L + 0 * PLSTR) = pa[0];
    *(bf8v*)(L + 1 * PLSTR) = pa[1];
    *(bf8v*)(L + 2 * PLSTR) = pa[2];
    *(bf8v*)(L + 3 * PLSTR) = pa[3];
  };
  auto compute = [&](int buf) {
    const u16* L = lds + buf * BUF4;
    int r0 = (wr * 32 + (lane & 15)) * LSTR + (lane >> 4) * 8;
    int c0 = (wc * 32 + (lane & 15)) * LSTR + (lane >> 4) * 8;
    bf8v ar[2], ai[2], br[2], bi[2];
    ar[0] = *(const bf8v*)(L + 0 * PLSTR + r0);
    ar[1] = *(const bf8v*)(L + 0 * PLSTR + r0 + 16 * LSTR);
    ai[0] = *(const bf8v*)(L + 1 * PLSTR + r0);
    ai[1] = *(const bf8v*)(L + 1 * PLSTR + r0 + 16 * LSTR);
    br[0] = *(const bf8v*)(L + 2 * PLSTR + c0);
    br[1] = *(const bf8v*)(L + 2 * PLSTR + c0 + 16 * LSTR);
    bi[0] = *(const bf8v*)(L + 3 * PLSTR + c0);
    bi[1] = *(const bf8v*)(L + 3 * PLSTR + c0 + 16 * LSTR);
    if constexpr (BNEG == 0) {
      bf8v nbr[2] = { neg8(br[0]), neg8(br[1]) };
      bf8v nbi[2] = { neg8(bi[0]), neg8(bi[1]) };
      #pragma unroll
      for (int mf = 0; mf < 2; ++mf)
        #pragma unroll
        for (int nf = 0; nf < 2; ++nf) {
          accR[mf][nf] = __builtin_amdgcn_mfma_f32_16x16x32_bf16(ar[mf], nbr[nf], accR[mf][nf], 0, 0, 0);
          accR[mf][nf] = __builtin_amdgcn_mfma_f32_16x16x32_bf16(ai[mf], nbi[nf], accR[mf][nf], 0, 0, 0);
          accI[mf][nf] = __builtin_amdgcn_mfma_f32_16x16x32_bf16(ar[mf], bi[nf],  accI[mf][nf], 0, 0, 0);
          accI[mf][nf] = __builtin_amdgcn_mfma_f32_16x16x32_bf16(ai[mf], nbr[nf], accI[mf][nf], 0, 0, 0);
        }
    } else {
      bf8v nbi[2] = { neg8(bi[0]), neg8(bi[1]) };
      #pragma unroll
      for (int mf = 0; mf < 2; ++mf)
        #pragma unroll
        for (int nf = 0; nf < 2; ++nf) {
          accR[mf][nf] = __builtin_amdgcn_mfma_f32_16x16x32_bf16(ar[mf], br[nf],  accR[mf][nf], 0, 0, 0);
          accR[mf][nf] = __builtin_amdgcn_mfma_f32_16x16x32_bf16(ai[mf], bi[nf],  accR[mf][nf], 0, 0, 0);
          accI[mf][nf] = __builtin_amdgcn_mfma_f32_16x16x32_bf16(ar[mf], nbi[nf], accI[mf][nf], 0, 0, 0);
          accI[mf][nf] = __builtin_amdgcn_mfma_f32_16x16x32_bf16(ai[mf], br[nf],  accI[mf][nf], 0, 0, 0);
        }
    }
  };

  gload(0); stolds(0); __syncthreads();
  int cur = 0;
  for (int t = 0; t < 32; ++t) {
    if (t < 31) gload((t + 1) * 32);
    compute(cur);
    if (t < 31) stolds(cur ^ 1);
    __syncthreads();
    cur ^= 1;
  }

  #pragma unroll
  for (int mf = 0; mf < 2; ++mf)
    #pragma unroll
    for (int nf = 0; nf < 2; ++nf) {
      int col = bn + wc * 32 + nf * 16 + (lane & 15);
      #pragma unroll
      for (int r = 0; r < 4; ++r) {
        int rowg = bm + wr * 32 + mf * 16 + (lane >> 4) * 4 + r;
        size_t o = (size_t)rowg * 1024 + col;
        if constexpr (EPI == 0) {
          Cr16[o] = f2bf(accR[mf][nf][r]);
          Ci16[o] = f2bf(accI[mf][nf][r]);
        } else {
          Crf[o] = accR[mf][nf][r] + bf2f(q1r[o]);
          Cif[o] = accI[mf][nf][r] + bf2f(q1i[o]);
        }
      }
    }
}

// ---------------------------------------------------------------------------
// Mt[d][k] = bf16( V[k][d]*exp(ls[d])*(1-alpha) + F[k][d]*alpha/32 )
// (tiled transpose; DFT basis is symmetric so computed in output orientation)
// ---------------------------------------------------------------------------
__global__ __launch_bounds__(TPB) void build_mt_k(
    const float* __restrict__ Vr, const float* __restrict__ Vi,
    const float* __restrict__ log_sigma, const float* __restrict__ dft_weight,
    u16* __restrict__ Mtr, u16* __restrict__ Mti)
{
  __shared__ float Tr[64][65], Ti[64][65];
  int tid = threadIdx.x;
  int k0 = blockIdx.x * 64, d0 = blockIdx.y * 64;
  int c = tid & 63, r4 = tid >> 6;
  for (int p = 0; p < 16; ++p) {
    int r = r4 + p * 4;                       // local k index
    Tr[r][c] = Vr[(size_t)(k0 + r) * 1024 + d0 + c];
    Ti[r][c] = Vi[(size_t)(k0 + r) * 1024 + d0 + c];
  }
  __syncthreads();
  float alpha = sigmoidf_(dft_weight[0]);
  const float isq = 0.03125f * alpha;
  for (int p = 0; p < 16; ++p) {
    int dl = r4 + p * 4;                      // local d index (output row)
    int d = d0 + dl, k = k0 + c;
    float w1 = expf(log_sigma[d]) * (1.0f - alpha);
    int mm = (k * d) & 1023;
    float ang = -6.283185307179586f * (float)mm * (1.0f / 1024.0f);
    float sn, cs;
    sincosf(ang, &sn, &cs);
    size_t o = (size_t)d * 1024 + k;
    Mtr[o] = f2bf(Tr[c][dl] * w1 + cs * isq);
    Mti[o] = f2bf(Ti[c][dl] * w1 + sn * isq);
  }
}

// ---------------------------------------------------------------------------
// per-d constants: op_decay, op_forcing, base_var
// ---------------------------------------------------------------------------
__global__ __launch_bounds__(TPB) void prep_k(
    const float* __restrict__ ld, const float* __restrict__ lf,
    const float* __restrict__ law_re, const float* __restrict__ law_im,
    const float* __restrict__ dt, const float* __restrict__ base_noise,
    float* __restrict__ od_re, float* __restrict__ od_im,
    float* __restrict__ of_re, float* __restrict__ of_im,
    float* __restrict__ bvar)
{
  int d = blockIdx.x * TPB + threadIdx.x;
  float dtr = dt[0];                              // DT_REF = 1.0
  float lre = tanhf(-expf(ld[d]) + law_re[d]) * 0.3f;
  float lim = lf[d] + law_im[d];
  float er = expf(lre * dtr);
  float sn, cs;
  sincosf(lim * dtr, &sn, &cs);
  float odr = er * cs, odi = er * sn;
  od_re[d] = odr;  od_im[d] = odi;
  float numr = odr - 1.0f, numi = odi;
  float denr = lre + 1e-8f, deni = lim;
  float inv = 1.0f / (denr * denr + deni * deni);
  of_re[d] = (numr * denr + numi * deni) * inv;
  of_im[d] = (numi * denr - numr * deni) * inv;
  float bn = base_noise[0];
  float bv = bn * bn * expm1f(2.0f * lre * dtr) / (2.0f * lre + 1e-8f);
  bvar[d] = fmaxf(bv, 0.0f);
}

// ---------------------------------------------------------------------------
// Wu1, Wu2 f32 -> bf16 planes
// ---------------------------------------------------------------------------
__global__ __launch_bounds__(TPB) void conv_w_k(
    const float* __restrict__ Wu1, const float* __restrict__ Wu2,
    u16* __restrict__ Wu1b, u16* __restrict__ Wu2b)
{
  int idx = blockIdx.x * TPB + threadIdx.x;     // 2 * 262144
  if (idx < 262144) Wu1b[idx] = f2bf(Wu1[idx]);
  else              Wu2b[idx - 262144] = f2bf(Wu2[idx - 262144]);
}

// ---------------------------------------------------------------------------
// small (16 x N) gemm: C[r,c] = sum_k [A0|A1][r,k] * Bw[c,k] + bias[c]
// ---------------------------------------------------------------------------
__global__ __launch_bounds__(TPB) void small_gemm_k(
    const float* __restrict__ A0, const float* __restrict__ A1,
    const float* __restrict__ Bw, const float* __restrict__ bias,
    float* __restrict__ C, int N, int act)
{
  int c = blockIdx.x * TPB + threadIdx.x;
  int r0 = blockIdx.y * 4;
  float acc[4] = {0.0f, 0.0f, 0.0f, 0.0f};
  const float* brow = Bw + (size_t)c * 2048;
  for (int k = 0; k < 1024; k += 4) {
    float4 b0 = *(const float4*)(brow + k);
    float4 b1 = *(const float4*)(brow + 1024 + k);
    #pragma unroll
    for (int r = 0; r < 4; ++r) {
      const float* a0 = A0 + (size_t)(r0 + r) * 1024 + k;
      const float* a1 = A1 + (size_t)(r0 + r) * 1024 + k;
      acc[r] += a0[0] * b0.x + a0[1] * b0.y + a0[2] * b0.z + a0[3] * b0.w
              + a1[0] * b1.x + a1[1] * b1.y + a1[2] * b1.z + a1[3] * b1.w;
    }
  }
  #pragma unroll
  for (int r = 0; r < 4; ++r) {
    float v = acc[r] + bias[c];
    if (act == 1) v = sigmoidf_(v);
    C[(size_t)(r0 + r) * N + c] = v;
  }
}

// ---------------------------------------------------------------------------
// flux_next = flux*fdecay + update ; FN planes + f32 output 1 = Re(flux_next)
// ---------------------------------------------------------------------------
__global__ __launch_bounds__(TPB) void flux_k(
    const float* __restrict__ xin,
    const float* __restrict__ flux_re, const float* __restrict__ flux_im,
    const float* __restrict__ decay_re, const float* __restrict__ decay_im,
    float* __restrict__ FNr, float* __restrict__ FNi,
    float* __restrict__ out1)
{
  int idx = blockIdx.x * TPB + threadIdx.x;     // 16 * 1024
  int b = idx >> 10, d = idx & 1023;
  float fdr = sigmoidf_(decay_re[d]);
  float fdi = decay_im[d];
  float fr = flux_re[idx], fi = flux_im[idx];
  float ur = xin[b * 2048 + d], ui = xin[b * 2048 + 1024 + d];
  float nr = fr * fdr - fi * fdi + ur;
  float ni = fr * fdi + fi * fdr + ui;
  FNr[idx] = nr;  FNi[idx] = ni;
  out1[idx] = nr;                                // f32, real part only
}

// ---------------------------------------------------------------------------
// x_tilde = x @ M (A: f32 x packed inline; B: Mt bf16 rows) + h_next epilogue
// writes Hr f32 and Hrb bf16
// ---------------------------------------------------------------------------
__global__ __launch_bounds__(TPB) void xmh_nt_k(
    const float* __restrict__ Xin,
    const u16* __restrict__ Mtr, const u16* __restrict__ Mti,
    const float* __restrict__ gate, const float* __restrict__ proj,
    const float* __restrict__ od_re, const float* __restrict__ od_im,
    const float* __restrict__ of_re, const float* __restrict__ of_im,
    const float* __restrict__ hp_re, const float* __restrict__ hp_im,
    float* __restrict__ Hr, u16* __restrict__ Hrb)
{
  __shared__ __align__(16) u16 lds[2 * BUF3];
  int tid = threadIdx.x;
  int bm = blockIdx.y * 64, bn = blockIdx.x * 64;
  int lane = tid & 63;
  int wr = (tid >> 7) & 1, wc = (tid >> 6) & 1;
  int row = tid >> 2, ch = (tid & 3) << 3;

  f32x4 accR[2][2] = {};
  f32x4 accI[2][2] = {};
  float4 pax[2];
  bf8v pb[2];

  auto gload = [&](int k0) {
    const float* p0 = Xin + (size_t)(bm + row) * 1024 + k0 + ch;
    pax[0] = *(const float4*)p0; pax[1] = *(const float4*)(p0 + 4);
    pb[0] = *(const bf8v*)(Mtr + (size_t)(bn + row) * 1024 + k0 + ch);
    pb[1] = *(const bf8v*)(Mti + (size_t)(bn + row) * 1024 + k0 + ch);
  };
  auto stolds = [&](int buf) {
    u16* L = lds + buf * BUF3 + row * LSTR + ch;
    pack8(pax[0], pax[1], L);
    *(bf8v*)(L + 1 * PLSTR) = pb[0];
    *(bf8v*)(L + 2 * PLSTR) = pb[1];
  };
  auto compute = [&](int buf) {
    const u16* L = lds + buf * BUF3;
    int r0 = (wr * 32 + (lane & 15)) * LSTR + (lane >> 4) * 8;
    int c0 = (wc * 32 + (lane & 15)) * LSTR + (lane >> 4) * 8;
    bf8v a[2], br[2], bi[2];
    a[0]  = *(const bf8v*)(L + 0 * PLSTR + r0);
    a[1]  = *(const bf8v*)(L + 0 * PLSTR + r0 + 16 * LSTR);
    br[0] = *(const bf8v*)(L + 1 * PLSTR + c0);
    br[1] = *(const bf8v*)(L + 1 * PLSTR + c0 + 16 * LSTR);
    bi[0] = *(const bf8v*)(L + 2 * PLSTR + c0);
    bi[1] = *(const bf8v*)(L + 2 * PLSTR + c0 + 16 * LSTR);
    #pragma unroll
    for (int mf = 0; mf < 2; ++mf)
      #pragma unroll
      for (int nf = 0; nf < 2; ++nf) {
        accR[mf][nf] = __builtin_amdgcn_mfma_f32_16x16x32_bf16(a[mf], br[nf], accR[mf][nf], 0, 0, 0);
        accI[mf][nf] = __builtin_amdgcn_mfma_f32_16x16x32_bf16(a[mf], bi[nf], accI[mf][nf], 0, 0, 0);
      }
  };

  gload(0); stolds(0); __syncthreads();
  int cur = 0;
  for (int t = 0; t < 32; ++t) {
    if (t < 31) gload((t + 1) * 32);
    compute(cur);
    if (t < 31) stolds(cur ^ 1);
    __syncthreads();
    cur ^= 1;
  }

  #pragma unroll
  for (int mf = 0; mf < 2; ++mf)
    #pragma unroll
    for (int nf = 0; nf < 2; ++nf) {
      int c = bn + wc * 32 + nf * 16 + (lane & 15);
      #pragma unroll
      for (int r = 0; r < 4; ++r) {
        int t = bm + wr * 32 + mf * 16 + (lane >> 4) * 4 + r;
        int b = t >> 8;                         // 64-row tile never straddles batch
        float g  = gate[b * 1024 + c];
        float sr = proj[b * 2048 + c];
        float si = proj[b * 2048 + 1024 + c];
        float fr = accR[mf][nf][r] * g + sr * (1.0f - g);
        float fi = accI[mf][nf][r] * g + si * (1.0f - g);
        float odr = od_re[c], odi = od_im[c];
        float ofr = of_re[c], ofi = of_im[c];
        size_t off = (size_t)t * 1024 + c;
        float pr = hp_re[off], pi = hp_im[off];
        float hv = pr * odr - pi * odi + fr * ofr - fi * ofi;  // real part
        Hr[off] = hv;
        Hrb[off] = f2bf(hv);
      }
    }
}

// ---------------------------------------------------------------------------
// real NT GEMM, bf16: C = A@B^T.  KI = K/32.
// EPI=0 (mlp1): silu(acc+bias) -> bf16, N-stride out.
// EPI=1 (final): u=softplus(acc+bias); out0 = Hr + nre*sqrt(bvar*u*0.5)
// ---------------------------------------------------------------------------
template<int KI, int EPI>
__global__ __launch_bounds__(TPB) void rgemm_nt_k(
    const u16* __restrict__ A, const u16* __restrict__ B,
    const float* __restrict__ bias,
    u16* __restrict__ C16, int N,
    const float* __restrict__ Hr, const float* __restrict__ nre,
    const float* __restrict__ bvar, float* __restrict__ out0)
{
  __shared__ __align__(16) u16 lds[2 * BUF2];
  const int K = KI * 32;
  int tid = threadIdx.x;
  int bm = blockIdx.y * 64, bn = blockIdx.x * 64;
  int lane = tid & 63;
  int wr = (tid >> 7) & 1, wc = (tid >> 6) & 1;
  int row = tid >> 2, ch = (tid & 3) << 3;

  f32x4 acc[2][2] = {};
  bf8v pa[2];

  auto gload = [&](int k0) {
    pa[0] = *(const bf8v*)(A + (size_t)(bm + row) * K + k0 + ch);
    pa[1] = *(const bf8v*)(B + (size_t)(bn + row) * K + k0 + ch);
  };
  auto stolds = [&](int buf) {
    u16* L = lds + buf * BUF2 + row * LSTR + ch;
    *(bf8v*)(L + 0 * PLSTR) = pa[0];
    *(bf8v*)(L + 1 * PLSTR) = pa[1];
  };
  auto compute = [&](int buf) {
    const u16* L = lds + buf * BUF2;
    int r0 = (wr * 32 + (lane & 15)) * LSTR + (lane >> 4) * 8;
    int c0 = (wc * 32 + (lane & 15)) * LSTR + (lane >> 4) * 8;
    bf8v a[2], b[2];
    a[0] = *(const bf8v*)(L + 0 * PLSTR + r0);
    a[1] = *(const bf8v*)(L + 0 * PLSTR + r0 + 16 * LSTR);
    b[0] = *(const bf8v*)(L + 1 * PLSTR + c0);
    b[1] = *(const bf8v*)(L + 1 * PLSTR + c0 + 16 * LSTR);
    #pragma unroll
    for (int mf = 0; mf < 2; ++mf)
      #pragma unroll
      for (int nf = 0; nf < 2; ++nf)
        acc[mf][nf] = __builtin_amdgcn_mfma_f32_16x16x32_bf16(a[mf], b[nf], acc[mf][nf], 0, 0, 0);
  };

  gload(0); stolds(0); __syncthreads();
  int cur = 0;
  for (int t = 0; t < KI; ++t) {
    if (t < KI - 1) gload((t + 1) * 32);
    compute(cur);
    if (t < KI - 1) stolds(cur ^ 1);
    __syncthreads();
    cur ^= 1;
  }

  #pragma unroll
  for (int mf = 0; mf < 2; ++mf)
    #pragma unroll
    for (int nf = 0; nf < 2; ++nf) {
      int c = bn + wc * 32 + nf * 16 + (lane & 15);
      #pragma unroll
      for (int r = 0; r < 4; ++r) {
        int t = bm + wr * 32 + mf * 16 + (lane >> 4) * 4 + r;
        float v = acc[mf][nf][r] + bias[c];
        if constexpr (EPI == 0) {
          v = v * sigmoidf_(v);                       // silu
          C16[(size_t)t * N + c] = f2bf(v);
        } else {
          float u = (v > 20.0f) ? v : log1pf(expf(v));    // softplus
          float sc = sqrtf(bvar[c] * u) * 0.7071067811865476f;
          size_t off = (size_t)t * 1024 + c;
          out0[off] = Hr[off] + nre[off] * sc;
        }
      }
    }
}

// ---------------------------------------------------------------------------
extern "C" void kernel_launch(void* const* d_in, const int* in_sizes, int n_in,
                              void* d_out, int out_size, void* d_ws, size_t ws_size,
                              hipStream_t stream) {
  (void)in_sizes; (void)n_in; (void)out_size;

  const float* x_input    = (const float*)d_in[0];
  const float* h_prev_re  = (const float*)d_in[1];
  const float* h_prev_im  = (const float*)d_in[2];
  const float* xg_re      = (const float*)d_in[3];
  const float* xg_im      = (const float*)d_in[4];
  const float* flux_re    = (const float*)d_in[5];
  const float* flux_im    = (const float*)d_in[6];
  const float* dt         = (const float*)d_in[7];
  const float* v_raw_re   = (const float*)d_in[10];
  const float* v_raw_im   = (const float*)d_in[11];
  const float* log_sigma  = (const float*)d_in[12];
  const float* dft_weight = (const float*)d_in[13];
  const float* decay_re   = (const float*)d_in[14];
  const float* decay_im   = (const float*)d_in[15];
  const float* Wi_in      = (const float*)d_in[16];
  const float* bi         = (const float*)d_in[17];
  const float* Wo         = (const float*)d_in[18];
  const float* bo         = (const float*)d_in[19];
  const float* Wg         = (const float*)d_in[20];
  const float* bg         = (const float*)d_in[21];
  const float* ld         = (const float*)d_in[22];
  const float* lf         = (const float*)d_in[23];
  const float* law_re     = (const float*)d_in[24];
  const float* law_im     = (const float*)d_in[25];
  const float* base_noise = (const float*)d_in[26];
  const float* Wu1        = (const float*)d_in[27];
  const float* bu1        = (const float*)d_in[28];
  const float* Wu2        = (const float*)d_in[29];
  const float* bu2        = (const float*)d_in[30];
  const float* noise_re   = (const float*)d_in[31];

  // --- workspace: 16 bf16-sized planes (2MB each) = 32MB --------------------
  const size_t PL16 = 1024ull * 1024ull;        // u16 per plane
  if (ws_size < 16 * PL16 * 2) return;          // too small -> zeros (diagnostic)

  u16* P = (u16*)d_ws;
  u16* Ar  = P + 0 * PL16;   u16* Ai  = P + 1 * PL16;
  u16* A2r = P + 2 * PL16;   u16* A2i = P + 3 * PL16;
  u16* A3r = P + 4 * PL16;   u16* A3i = P + 5 * PL16;
  u16* A4r = P + 6 * PL16;   u16* A4i = P + 7 * PL16;
  u16* q1r = P + 8 * PL16;   u16* q1i = P + 9 * PL16;
  u16* q2r = P + 10 * PL16;  u16* q2i = P + 11 * PL16;
  // liveness reuse (stream-ordered):
  float* Vr = (float*)(P + 0 * PL16);   // 4MB over P0,P1   (A dead after build_q)
  float* Vi = (float*)(P + 2 * PL16);   // 4MB over P2,P3   (A2 dead after build_q)
  u16* Mtr  = P + 8 * PL16;             // over q1 (dead after G4)
  u16* Mti  = P + 9 * PL16;
  float* Hr = (float*)(P + 0 * PL16);   // 16MB over P0..P7 (V,A3,A4 dead after build_mt)
  u16* Hrb  = P + 10 * PL16;            // 8MB over q2 (dead) + P12,P13
  u16* mlp1b = P + 14 * PL16;           // 4096x256
  u16* Wu1b  = P + 15 * PL16;           // 262144 u16
  u16* Wu2b  = Wu1b + 262144;
  float* sm  = (float*)(P + 15 * PL16 + 524288);
  float* xin  = sm;                     // 16x2048
  float* proj = xin + 32768;            // 16x2048
  float* FNr  = proj + 32768;           // 16x1024
  float* FNi  = FNr + 16384;
  float* gate = FNi + 16384;            // 16x1024
  float* od_re = gate + 16384;
  float* od_im = od_re + 1024;
  float* of_re = od_im + 1024;
  float* of_im = of_re + 1024;
  float* bvar  = of_im + 1024;

  float* out0f = (float*)d_out;                       // 4096x1024 f32 (real)
  float* out1f = out0f + (size_t)4096 * 1024;         // 16x1024 f32 (real)

  // --- Cayley via degree-7 polynomial: V = q1 + q2@A^4, err <= 2.2e-3 -------
  build_a_k<<<4096, TPB, 0, stream>>>(v_raw_re, v_raw_im, Ar, Ai);
  // A2 = A@A   (B-plane = A: BNEG=0)
  cgemm_nt_k<0, 0><<<dim3(16, 16), TPB, 0, stream>>>(Ar, Ai, Ar, Ai, A2r, A2i,
                                                     nullptr, nullptr, nullptr, nullptr);
  // A3 = A@A2  (B-plane = A2: conj, BNEG=1)
  cgemm_nt_k<1, 0><<<dim3(16, 16), TPB, 0, stream>>>(Ar, Ai, A2r, A2i, A3r, A3i,
                                                     nullptr, nullptr, nullptr, nullptr);
  // A4 = A2@A2 (BNEG=1)
  cgemm_nt_k<1, 0><<<dim3(16, 16), TPB, 0, stream>>>(A2r, A2i, A2r, A2i, A4r, A4i,
                                                     nullptr, nullptr, nullptr, nullptr);
  build_q_k<<<4096, TPB, 0, stream>>>(Ar, Ai, A2r, A2i, A3r, A3i, q1r, q1i, q2r, q2i);
  // V = q2@A4 + q1 (BNEG=1, f32 out over A/A2 region)
  cgemm_nt_k<1, 1><<<dim3(16, 16), TPB, 0, stream>>>(q2r, q2i, A4r, A4i,
                                                     nullptr, nullptr, q1r, q1i, Vr, Vi);
  build_mt_k<<<dim3(16, 16), TPB, 0, stream>>>(Vr, Vi, log_sigma, dft_weight, Mtr, Mti);

  // --- per-d constants + weight conversion + flux/source/gate chain ---------
  prep_k<<<4, TPB, 0, stream>>>(ld, lf, law_re, law_im, dt, base_noise,
                                od_re, od_im, of_re, of_im, bvar);
  conv_w_k<<<2048, TPB, 0, stream>>>(Wu1, Wu2, Wu1b, Wu2b);
  small_gemm_k<<<dim3(8, 4), TPB, 0, stream>>>(xg_re, xg_im, Wi_in, bi, xin, 2048, 0);
  flux_k<<<64, TPB, 0, stream>>>(xin, flux_re, flux_im, decay_re, decay_im,
                                 FNr, FNi, out1f);
  small_gemm_k<<<dim3(8, 4), TPB, 0, stream>>>(FNr, FNi, Wo, bo, proj, 2048, 0);
  small_gemm_k<<<dim3(4, 4), TPB, 0, stream>>>(FNr, FNi, Wg, bg, gate, 1024, 1);

  // --- x_tilde = x@M fused with h_next epilogue -> Hr f32 + Hrb bf16 --------
  xmh_nt_k<<<dim3(16, 64), TPB, 0, stream>>>(x_input, Mtr, Mti, gate, proj,
                                             od_re, od_im, of_re, of_im,
                                             h_prev_re, h_prev_im, Hr, Hrb);

  // --- u-MLP (MFMA) + final noisy output ------------------------------------
  rgemm_nt_k<32, 0><<<dim3(4, 64), TPB, 0, stream>>>(Hrb, Wu1b, bu1, mlp1b, 256,
                                                     nullptr, nullptr, nullptr, nullptr);
  rgemm_nt_k<8, 1><<<dim3(16, 64), TPB, 0, stream>>>(mlp1b, Wu2b, bu2, nullptr, 1024,
                                                     Hr, noise_re, bvar, out0f);
}

// Round 8
// 244.011 us; speedup vs baseline: 10.5294x; 1.7547x over previous
//
#include <hip/hip_runtime.h>
#include <cstddef>

#define TPB 256

typedef short bf8v  __attribute__((ext_vector_type(8)));   // 8 bf16 bit-patterns
typedef float f32x4 __attribute__((ext_vector_type(4)));
typedef unsigned short u16;

#define LSTR 40      // LDS row stride in u16 (80B: 16B-aligned, 2-way banks)
#define PLSTR 2560   // 64*LSTR
#define BUF4 10240   // 4 planes (complex NT gemm)
#define BUF3 7680    // 3 planes (xmh)
#define BUF2 5120    // 2 planes (real NT gemm)
#define BUF1 2560    // 1 plane (small gemm)

static __device__ __forceinline__ u16 f2bf(float x) {
  unsigned int u = __float_as_uint(x);
  u = (u + 0x7FFFu + ((u >> 16) & 1u)) >> 16;   // RNE f32 -> bf16
  return (u16)u;
}
static __device__ __forceinline__ float bf2f(u16 x) {
  return __uint_as_float(((unsigned int)x) << 16);
}
static __device__ __forceinline__ float sigmoidf_(float x) {
  return 1.0f / (1.0f + expf(-x));
}
static __device__ __forceinline__ bf8v neg8(bf8v a) {
  #pragma unroll
  for (int i = 0; i < 8; ++i) a[i] ^= (short)0x8000;
  return a;
}
static __device__ __forceinline__ void pack8(const float4& x, const float4& y,
                                             u16* dst) {
  unsigned int* d = (unsigned int*)dst;
  d[0] = ((unsigned)f2bf(x.y) << 16) | f2bf(x.x);
  d[1] = ((unsigned)f2bf(x.w) << 16) | f2bf(x.z);
  d[2] = ((unsigned)f2bf(y.y) << 16) | f2bf(y.x);
  d[3] = ((unsigned)f2bf(y.w) << 16) | f2bf(y.z);
}

// ---------------------------------------------------------------------------
// A = (v - v^T)re + i(v + v^T)im  -> bf16 planes.  (Ar antisym, Ai sym)
// ---------------------------------------------------------------------------
__global__ __launch_bounds__(TPB) void build_a_k(
    const float* __restrict__ vre, const float* __restrict__ vim,
    u16* __restrict__ Ar, u16* __restrict__ Ai)
{
  int idx = blockIdx.x * TPB + threadIdx.x;
  int i = idx >> 10, j = idx & 1023;
  Ar[idx] = f2bf(vre[idx] - vre[j * 1024 + i]);
  Ai[idx] = f2bf(vim[idx] + vim[j * 1024 + i]);
}

// ---------------------------------------------------------------------------
// q1 = I - 2A + 2A^2 - 2A^3 ; q2 = q1 + I   (bf16 in/out)
// ---------------------------------------------------------------------------
__global__ __launch_bounds__(TPB) void build_q_k(
    const u16* __restrict__ Ar, const u16* __restrict__ Ai,
    const u16* __restrict__ A2r, const u16* __restrict__ A2i,
    const u16* __restrict__ A3r, const u16* __restrict__ A3i,
    u16* __restrict__ q1r, u16* __restrict__ q1i,
    u16* __restrict__ q2r, u16* __restrict__ q2i)
{
  int idx = blockIdx.x * TPB + threadIdx.x;
  int i = idx >> 10, j = idx & 1023;
  float dg = (i == j) ? 1.0f : 0.0f;
  float r = dg - 2.0f * bf2f(Ar[idx]) + 2.0f * bf2f(A2r[idx]) - 2.0f * bf2f(A3r[idx]);
  float m = -2.0f * bf2f(Ai[idx]) + 2.0f * bf2f(A2i[idx]) - 2.0f * bf2f(A3i[idx]);
  q1r[idx] = f2bf(r);      q1i[idx] = f2bf(m);
  q2r[idx] = f2bf(r + dg); q2i[idx] = f2bf(m);
}

// ---------------------------------------------------------------------------
// complex NT GEMM (1024^3), bf16: C = A@B_true.
//   BNEG=0 (B-plane = A itself):  B_true = (-b^r, +b^i)   [A^T = -conj(A)]
//   BNEG=1 (B-plane = A^{2k}):    B_true = (+b^r, -b^i)   [(A^2k)^T = conj]
// EPI=0: store bf16.  EPI=1: C += q1 (bf16 reload), store f32.
// ---------------------------------------------------------------------------
template<int BNEG, int EPI>
__global__ __launch_bounds__(TPB) void cgemm_nt_k(
    const u16* __restrict__ Apr, const u16* __restrict__ Api,
    const u16* __restrict__ Bpr, const u16* __restrict__ Bpi,
    u16* __restrict__ Cr16, u16* __restrict__ Ci16,
    const u16* __restrict__ q1r, const u16* __restrict__ q1i,
    float* __restrict__ Crf, float* __restrict__ Cif)
{
  __shared__ __align__(16) u16 lds[2 * BUF4];
  int tid = threadIdx.x;
  int bm = blockIdx.y * 64, bn = blockIdx.x * 64;
  int lane = tid & 63;
  int wr = (tid >> 7) & 1, wc = (tid >> 6) & 1;
  int row = tid >> 2, ch = (tid & 3) << 3;

  f32x4 accR[2][2] = {};
  f32x4 accI[2][2] = {};
  bf8v pa[4];

  auto gload = [&](int k0) {
    pa[0] = *(const bf8v*)(Apr + (size_t)(bm + row) * 1024 + k0 + ch);
    pa[1] = *(const bf8v*)(Api + (size_t)(bm + row) * 1024 + k0 + ch);
    pa[2] = *(const bf8v*)(Bpr + (size_t)(bn + row) * 1024 + k0 + ch);
    pa[3] = *(const bf8v*)(Bpi + (size_t)(bn + row) * 1024 + k0 + ch);
  };
  auto stolds = [&](int buf) {
    u16* L = lds + buf * BUF4 + row * LSTR + ch;
    *(bf8v*)(L + 0 * PLSTR) = pa[0];
    *(bf8v*)(L + 1 * PLSTR) = pa[1];
    *(bf8v*)(L + 2 * PLSTR) = pa[2];
    *(bf8v*)(L + 3 * PLSTR) = pa[3];
  };
  auto compute = [&](int buf) {
    const u16* L = lds + buf * BUF4;
    int r0 = (wr * 32 + (lane & 15)) * LSTR + (lane >> 4) * 8;
    int c0 = (wc * 32 + (lane & 15)) * LSTR + (lane >> 4) * 8;
    bf8v ar[2], ai[2], br[2], bi[2];
    ar[0] = *(const bf8v*)(L + 0 * PLSTR + r0);
    ar[1] = *(const bf8v*)(L + 0 * PLSTR + r0 + 16 * LSTR);
    ai[0] = *(const bf8v*)(L + 1 * PLSTR + r0);
    ai[1] = *(const bf8v*)(L + 1 * PLSTR + r0 + 16 * LSTR);
    br[0] = *(const bf8v*)(L + 2 * PLSTR + c0);
    br[1] = *(const bf8v*)(L + 2 * PLSTR + c0 + 16 * LSTR);
    bi[0] = *(const bf8v*)(L + 3 * PLSTR + c0);
    bi[1] = *(const bf8v*)(L + 3 * PLSTR + c0 + 16 * LSTR);
    if constexpr (BNEG == 0) {
      bf8v nbr[2] = { neg8(br[0]), neg8(br[1]) };
      bf8v nbi[2] = { neg8(bi[0]), neg8(bi[1]) };
      #pragma unroll
      for (int mf = 0; mf < 2; ++mf)
        #pragma unroll
        for (int nf = 0; nf < 2; ++nf) {
          accR[mf][nf] = __builtin_amdgcn_mfma_f32_16x16x32_bf16(ar[mf], nbr[nf], accR[mf][nf], 0, 0, 0);
          accR[mf][nf] = __builtin_amdgcn_mfma_f32_16x16x32_bf16(ai[mf], nbi[nf], accR[mf][nf], 0, 0, 0);
          accI[mf][nf] = __builtin_amdgcn_mfma_f32_16x16x32_bf16(ar[mf], bi[nf],  accI[mf][nf], 0, 0, 0);
          accI[mf][nf] = __builtin_amdgcn_mfma_f32_16x16x32_bf16(ai[mf], nbr[nf], accI[mf][nf], 0, 0, 0);
        }
    } else {
      bf8v nbi[2] = { neg8(bi[0]), neg8(bi[1]) };
      #pragma unroll
      for (int mf = 0; mf < 2; ++mf)
        #pragma unroll
        for (int nf = 0; nf < 2; ++nf) {
          accR[mf][nf] = __builtin_amdgcn_mfma_f32_16x16x32_bf16(ar[mf], br[nf],  accR[mf][nf], 0, 0, 0);
          accR[mf][nf] = __builtin_amdgcn_mfma_f32_16x16x32_bf16(ai[mf], bi[nf],  accR[mf][nf], 0, 0, 0);
          accI[mf][nf] = __builtin_amdgcn_mfma_f32_16x16x32_bf16(ar[mf], nbi[nf], accI[mf][nf], 0, 0, 0);
          accI[mf][nf] = __builtin_amdgcn_mfma_f32_16x16x32_bf16(ai[mf], br[nf],  accI[mf][nf], 0, 0, 0);
        }
    }
  };

  gload(0); stolds(0); __syncthreads();
  int cur = 0;
  for (int t = 0; t < 32; ++t) {
    if (t < 31) gload((t + 1) * 32);
    compute(cur);
    if (t < 31) stolds(cur ^ 1);
    __syncthreads();
    cur ^= 1;
  }

  #pragma unroll
  for (int mf = 0; mf < 2; ++mf)
    #pragma unroll
    for (int nf = 0; nf < 2; ++nf) {
      int col = bn + wc * 32 + nf * 16 + (lane & 15);
      #pragma unroll
      for (int r = 0; r < 4; ++r) {
        int rowg = bm + wr * 32 + mf * 16 + (lane >> 4) * 4 + r;
        size_t o = (size_t)rowg * 1024 + col;
        if constexpr (EPI == 0) {
          Cr16[o] = f2bf(accR[mf][nf][r]);
          Ci16[o] = f2bf(accI[mf][nf][r]);
        } else {
          Crf[o] = accR[mf][nf][r] + bf2f(q1r[o]);
          Cif[o] = accI[mf][nf][r] + bf2f(q1i[o]);
        }
      }
    }
}

// ---------------------------------------------------------------------------
// Mt[d][k] = bf16( V[k][d]*exp(ls[d])*(1-alpha) + F[k][d]*alpha/32 )
// ---------------------------------------------------------------------------
__global__ __launch_bounds__(TPB) void build_mt_k(
    const float* __restrict__ Vr, const float* __restrict__ Vi,
    const float* __restrict__ log_sigma, const float* __restrict__ dft_weight,
    u16* __restrict__ Mtr, u16* __restrict__ Mti)
{
  __shared__ float Tr[64][65], Ti[64][65];
  int tid = threadIdx.x;
  int k0 = blockIdx.x * 64, d0 = blockIdx.y * 64;
  int c = tid & 63, r4 = tid >> 6;
  for (int p = 0; p < 16; ++p) {
    int r = r4 + p * 4;                       // local k index
    Tr[r][c] = Vr[(size_t)(k0 + r) * 1024 + d0 + c];
    Ti[r][c] = Vi[(size_t)(k0 + r) * 1024 + d0 + c];
  }
  __syncthreads();
  float alpha = sigmoidf_(dft_weight[0]);
  const float isq = 0.03125f * alpha;
  for (int p = 0; p < 16; ++p) {
    int dl = r4 + p * 4;                      // local d index (output row)
    int d = d0 + dl, k = k0 + c;
    float w1 = expf(log_sigma[d]) * (1.0f - alpha);
    int mm = (k * d) & 1023;
    float ang = -6.283185307179586f * (float)mm * (1.0f / 1024.0f);
    float sn, cs;
    sincosf(ang, &sn, &cs);
    size_t o = (size_t)d * 1024 + k;
    Mtr[o] = f2bf(Tr[c][dl] * w1 + cs * isq);
    Mti[o] = f2bf(Ti[c][dl] * w1 + sn * isq);
  }
}

// ---------------------------------------------------------------------------
// per-d constants: op_decay, op_forcing, base_var
// ---------------------------------------------------------------------------
__global__ __launch_bounds__(TPB) void prep_k(
    const float* __restrict__ ld, const float* __restrict__ lf,
    const float* __restrict__ law_re, const float* __restrict__ law_im,
    const float* __restrict__ dt, const float* __restrict__ base_noise,
    float* __restrict__ od_re, float* __restrict__ od_im,
    float* __restrict__ of_re, float* __restrict__ of_im,
    float* __restrict__ bvar)
{
  int d = blockIdx.x * TPB + threadIdx.x;
  float dtr = dt[0];                              // DT_REF = 1.0
  float lre = tanhf(-expf(ld[d]) + law_re[d]) * 0.3f;
  float lim = lf[d] + law_im[d];
  float er = expf(lre * dtr);
  float sn, cs;
  sincosf(lim * dtr, &sn, &cs);
  float odr = er * cs, odi = er * sn;
  od_re[d] = odr;  od_im[d] = odi;
  float numr = odr - 1.0f, numi = odi;
  float denr = lre + 1e-8f, deni = lim;
  float inv = 1.0f / (denr * denr + deni * deni);
  of_re[d] = (numr * denr + numi * deni) * inv;
  of_im[d] = (numi * denr - numr * deni) * inv;
  float bn = base_noise[0];
  float bv = bn * bn * expm1f(2.0f * lre * dtr) / (2.0f * lre + 1e-8f);
  bvar[d] = fmaxf(bv, 0.0f);
}

// ---------------------------------------------------------------------------
// Wu1, Wu2 f32 -> bf16 planes
// ---------------------------------------------------------------------------
__global__ __launch_bounds__(TPB) void conv_w_k(
    const float* __restrict__ Wu1, const float* __restrict__ Wu2,
    u16* __restrict__ Wu1b, u16* __restrict__ Wu2b)
{
  int idx = blockIdx.x * TPB + threadIdx.x;     // 2 * 262144
  if (idx < 262144) Wu1b[idx] = f2bf(Wu1[idx]);
  else              Wu2b[idx - 262144] = f2bf(Wu2[idx - 262144]);
}

// ---------------------------------------------------------------------------
// M=16 split-K MFMA GEMM: Pp[s][r][c] = sum_{k in slice s} A[r][k]*Bw[c][k]
// A = [A0|A1] (16x1024 f32 each), Bw = N x 2048 f32 (row-major, k fastest).
// grid (N/64, 8); block = 4 waves, wave w -> cols c0+16w..+15; slice = 256 k.
// B staged f32->bf16 LDS (coalesced float4); A frag packed in-register (L2 hot).
// ---------------------------------------------------------------------------
__global__ __launch_bounds__(TPB) void sgemm16_k(
    const float* __restrict__ A0, const float* __restrict__ A1,
    const float* __restrict__ Bw, float* __restrict__ Pp, int N)
{
  __shared__ __align__(16) u16 lds[2 * BUF1];
  int tid = threadIdx.x;
  int c0 = blockIdx.x * 64;
  int kbase = blockIdx.y * 256;
  int lane = tid & 63;
  int w = tid >> 6;
  int row = tid >> 2, kq = (tid & 3) << 3;

  f32x4 acc = {};
  float4 pb0, pb1;

  auto gload = [&](int k0) {
    const float* p = Bw + (size_t)(c0 + row) * 2048 + k0 + kq;
    pb0 = *(const float4*)p; pb1 = *(const float4*)(p + 4);
  };
  auto stolds = [&](int buf) {
    pack8(pb0, pb1, lds + buf * BUF1 + row * LSTR + kq);
  };
  auto compute = [&](int buf, int k0) {
    int ar = lane & 15;
    int ko = (lane >> 4) * 8;
    const float* ap = (k0 < 1024) ? (A0 + (size_t)ar * 1024 + k0 + ko)
                                  : (A1 + (size_t)ar * 1024 + k0 + ko - 1024);
    float4 a0 = *(const float4*)ap, a1 = *(const float4*)(ap + 4);
    u16 abuf[8];
    pack8(a0, a1, abuf);
    bf8v af = *(bf8v*)abuf;
    const u16* L = lds + buf * BUF1;
    bf8v bfr = *(const bf8v*)(L + (w * 16 + (lane & 15)) * LSTR + ko);
    acc = __builtin_amdgcn_mfma_f32_16x16x32_bf16(af, bfr, acc, 0, 0, 0);
  };

  gload(kbase); stolds(0); __syncthreads();
  int cur = 0;
  for (int t = 0; t < 8; ++t) {
    int k0 = kbase + t * 32;
    if (t < 7) gload(k0 + 32);
    compute(cur, k0);
    if (t < 7) stolds(cur ^ 1);
    __syncthreads();
    cur ^= 1;
  }

  int c = c0 + w * 16 + (lane & 15);
  #pragma unroll
  for (int r = 0; r < 4; ++r) {
    int rr = (lane >> 4) * 4 + r;
    Pp[((size_t)blockIdx.y * 16 + rr) * N + c] = acc[r];
  }
}

// ---------------------------------------------------------------------------
// reduce 8 K-slice partials + bias (+ optional sigmoid) -> out [16][N]
// ---------------------------------------------------------------------------
__global__ __launch_bounds__(TPB) void red16_k(
    const float* __restrict__ Pp, const float* __restrict__ bias,
    float* __restrict__ out, int N, int act)
{
  int idx = blockIdx.x * TPB + threadIdx.x;   // 16*N
  int c = idx & (N - 1);
  float v = bias[c];
  #pragma unroll
  for (int s = 0; s < 8; ++s) v += Pp[(size_t)s * 16 * N + idx];
  if (act == 1) v = sigmoidf_(v);
  out[idx] = v;
}

// ---------------------------------------------------------------------------
// flux_next = flux*fdecay + update ; FN planes + f32 output 1 = Re(flux_next)
// ---------------------------------------------------------------------------
__global__ __launch_bounds__(TPB) void flux_k(
    const float* __restrict__ xin,
    const float* __restrict__ flux_re, const float* __restrict__ flux_im,
    const float* __restrict__ decay_re, const float* __restrict__ decay_im,
    float* __restrict__ FNr, float* __restrict__ FNi,
    float* __restrict__ out1)
{
  int idx = blockIdx.x * TPB + threadIdx.x;     // 16 * 1024
  int b = idx >> 10, d = idx & 1023;
  float fdr = sigmoidf_(decay_re[d]);
  float fdi = decay_im[d];
  float fr = flux_re[idx], fi = flux_im[idx];
  float ur = xin[b * 2048 + d], ui = xin[b * 2048 + 1024 + d];
  float nr = fr * fdr - fi * fdi + ur;
  float ni = fr * fdi + fi * fdr + ui;
  FNr[idx] = nr;  FNi[idx] = ni;
  out1[idx] = nr;                                // f32, real part only
}

// ---------------------------------------------------------------------------
// x_tilde = x @ M (A: f32 x packed inline; B: Mt bf16 rows) + h_next epilogue
// ---------------------------------------------------------------------------
__global__ __launch_bounds__(TPB) void xmh_nt_k(
    const float* __restrict__ Xin,
    const u16* __restrict__ Mtr, const u16* __restrict__ Mti,
    const float* __restrict__ gate, const float* __restrict__ proj,
    const float* __restrict__ od_re, const float* __restrict__ od_im,
    const float* __restrict__ of_re, const float* __restrict__ of_im,
    const float* __restrict__ hp_re, const float* __restrict__ hp_im,
    float* __restrict__ Hr, u16* __restrict__ Hrb)
{
  __shared__ __align__(16) u16 lds[2 * BUF3];
  int tid = threadIdx.x;
  int bm = blockIdx.y * 64, bn = blockIdx.x * 64;
  int lane = tid & 63;
  int wr = (tid >> 7) & 1, wc = (tid >> 6) & 1;
  int row = tid >> 2, ch = (tid & 3) << 3;

  f32x4 accR[2][2] = {};
  f32x4 accI[2][2] = {};
  float4 pax[2];
  bf8v pb[2];

  auto gload = [&](int k0) {
    const float* p0 = Xin + (size_t)(bm + row) * 1024 + k0 + ch;
    pax[0] = *(const float4*)p0; pax[1] = *(const float4*)(p0 + 4);
    pb[0] = *(const bf8v*)(Mtr + (size_t)(bn + row) * 1024 + k0 + ch);
    pb[1] = *(const bf8v*)(Mti + (size_t)(bn + row) * 1024 + k0 + ch);
  };
  auto stolds = [&](int buf) {
    u16* L = lds + buf * BUF3 + row * LSTR + ch;
    pack8(pax[0], pax[1], L);
    *(bf8v*)(L + 1 * PLSTR) = pb[0];
    *(bf8v*)(L + 2 * PLSTR) = pb[1];
  };
  auto compute = [&](int buf) {
    const u16* L = lds + buf * BUF3;
    int r0 = (wr * 32 + (lane & 15)) * LSTR + (lane >> 4) * 8;
    int c0 = (wc * 32 + (lane & 15)) * LSTR + (lane >> 4) * 8;
    bf8v a[2], br[2], bi[2];
    a[0]  = *(const bf8v*)(L + 0 * PLSTR + r0);
    a[1]  = *(const bf8v*)(L + 0 * PLSTR + r0 + 16 * LSTR);
    br[0] = *(const bf8v*)(L + 1 * PLSTR + c0);
    br[1] = *(const bf8v*)(L + 1 * PLSTR + c0 + 16 * LSTR);
    bi[0] = *(const bf8v*)(L + 2 * PLSTR + c0);
    bi[1] = *(const bf8v*)(L + 2 * PLSTR + c0 + 16 * LSTR);
    #pragma unroll
    for (int mf = 0; mf < 2; ++mf)
      #pragma unroll
      for (int nf = 0; nf < 2; ++nf) {
        accR[mf][nf] = __builtin_amdgcn_mfma_f32_16x16x32_bf16(a[mf], br[nf], accR[mf][nf], 0, 0, 0);
        accI[mf][nf] = __builtin_amdgcn_mfma_f32_16x16x32_bf16(a[mf], bi[nf], accI[mf][nf], 0, 0, 0);
      }
  };

  gload(0); stolds(0); __syncthreads();
  int cur = 0;
  for (int t = 0; t < 32; ++t) {
    if (t < 31) gload((t + 1) * 32);
    compute(cur);
    if (t < 31) stolds(cur ^ 1);
    __syncthreads();
    cur ^= 1;
  }

  #pragma unroll
  for (int mf = 0; mf < 2; ++mf)
    #pragma unroll
    for (int nf = 0; nf < 2; ++nf) {
      int c = bn + wc * 32 + nf * 16 + (lane & 15);
      #pragma unroll
      for (int r = 0; r < 4; ++r) {
        int t = bm + wr * 32 + mf * 16 + (lane >> 4) * 4 + r;
        int b = t >> 8;                         // 64-row tile never straddles batch
        float g  = gate[b * 1024 + c];
        float sr = proj[b * 2048 + c];
        float si = proj[b * 2048 + 1024 + c];
        float fr = accR[mf][nf][r] * g + sr * (1.0f - g);
        float fi = accI[mf][nf][r] * g + si * (1.0f - g);
        float odr = od_re[c], odi = od_im[c];
        float ofr = of_re[c], ofi = of_im[c];
        size_t off = (size_t)t * 1024 + c;
        float pr = hp_re[off], pi = hp_im[off];
        float hv = pr * odr - pi * odi + fr * ofr - fi * ofi;  // real part
        Hr[off] = hv;
        Hrb[off] = f2bf(hv);
      }
    }
}

// ---------------------------------------------------------------------------
// real NT GEMM, bf16: C = A@B^T.  KI = K/32.
// EPI=0 (mlp1): silu(acc+bias) -> bf16.  EPI=1 (final): softplus->noise->out0
// ---------------------------------------------------------------------------
template<int KI, int EPI>
__global__ __launch_bounds__(TPB) void rgemm_nt_k(
    const u16* __restrict__ A, const u16* __restrict__ B,
    const float* __restrict__ bias,
    u16* __restrict__ C16, int N,
    const float* __restrict__ Hr, const float* __restrict__ nre,
    const float* __restrict__ bvar, float* __restrict__ out0)
{
  __shared__ __align__(16) u16 lds[2 * BUF2];
  const int K = KI * 32;
  int tid = threadIdx.x;
  int bm = blockIdx.y * 64, bn = blockIdx.x * 64;
  int lane = tid & 63;
  int wr = (tid >> 7) & 1, wc = (tid >> 6) & 1;
  int row = tid >> 2, ch = (tid & 3) << 3;

  f32x4 acc[2][2] = {};
  bf8v pa[2];

  auto gload = [&](int k0) {
    pa[0] = *(const bf8v*)(A + (size_t)(bm + row) * K + k0 + ch);
    pa[1] = *(const bf8v*)(B + (size_t)(bn + row) * K + k0 + ch);
  };
  auto stolds = [&](int buf) {
    u16* L = lds + buf * BUF2 + row * LSTR + ch;
    *(bf8v*)(L + 0 * PLSTR) = pa[0];
    *(bf8v*)(L + 1 * PLSTR) = pa[1];
  };
  auto compute = [&](int buf) {
    const u16* L = lds + buf * BUF2;
    int r0 = (wr * 32 + (lane & 15)) * LSTR + (lane >> 4) * 8;
    int c0 = (wc * 32 + (lane & 15)) * LSTR + (lane >> 4) * 8;
    bf8v a[2], b[2];
    a[0] = *(const bf8v*)(L + 0 * PLSTR + r0);
    a[1] = *(const bf8v*)(L + 0 * PLSTR + r0 + 16 * LSTR);
    b[0] = *(const bf8v*)(L + 1 * PLSTR + c0);
    b[1] = *(const bf8v*)(L + 1 * PLSTR + c0 + 16 * LSTR);
    #pragma unroll
    for (int mf = 0; mf < 2; ++mf)
      #pragma unroll
      for (int nf = 0; nf < 2; ++nf)
        acc[mf][nf] = __builtin_amdgcn_mfma_f32_16x16x32_bf16(a[mf], b[nf], acc[mf][nf], 0, 0, 0);
  };

  gload(0); stolds(0); __syncthreads();
  int cur = 0;
  for (int t = 0; t < KI; ++t) {
    if (t < KI - 1) gload((t + 1) * 32);
    compute(cur);
    if (t < KI - 1) stolds(cur ^ 1);
    __syncthreads();
    cur ^= 1;
  }

  #pragma unroll
  for (int mf = 0; mf < 2; ++mf)
    #pragma unroll
    for (int nf = 0; nf < 2; ++nf) {
      int c = bn + wc * 32 + nf * 16 + (lane & 15);
      #pragma unroll
      for (int r = 0; r < 4; ++r) {
        int t = bm + wr * 32 + mf * 16 + (lane >> 4) * 4 + r;
        float v = acc[mf][nf][r] + bias[c];
        if constexpr (EPI == 0) {
          v = v * sigmoidf_(v);                       // silu
          C16[(size_t)t * N + c] = f2bf(v);
        } else {
          float u = (v > 20.0f) ? v : log1pf(expf(v));    // softplus
          float sc = sqrtf(bvar[c] * u) * 0.7071067811865476f;
          size_t off = (size_t)t * 1024 + c;
          out0[off] = Hr[off] + nre[off] * sc;
        }
      }
    }
}

// ---------------------------------------------------------------------------
extern "C" void kernel_launch(void* const* d_in, const int* in_sizes, int n_in,
                              void* d_out, int out_size, void* d_ws, size_t ws_size,
                              hipStream_t stream) {
  (void)in_sizes; (void)n_in; (void)out_size;

  const float* x_input    = (const float*)d_in[0];
  const float* h_prev_re  = (const float*)d_in[1];
  const float* h_prev_im  = (const float*)d_in[2];
  const float* xg_re      = (const float*)d_in[3];
  const float* xg_im      = (const float*)d_in[4];
  const float* flux_re    = (const float*)d_in[5];
  const float* flux_im    = (const float*)d_in[6];
  const float* dt         = (const float*)d_in[7];
  const float* v_raw_re   = (const float*)d_in[10];
  const float* v_raw_im   = (const float*)d_in[11];
  const float* log_sigma  = (const float*)d_in[12];
  const float* dft_weight = (const float*)d_in[13];
  const float* decay_re   = (const float*)d_in[14];
  const float* decay_im   = (const float*)d_in[15];
  const float* Wi_in      = (const float*)d_in[16];
  const float* bi         = (const float*)d_in[17];
  const float* Wo         = (const float*)d_in[18];
  const float* bo         = (const float*)d_in[19];
  const float* Wg         = (const float*)d_in[20];
  const float* bg         = (const float*)d_in[21];
  const float* ld         = (const float*)d_in[22];
  const float* lf         = (const float*)d_in[23];
  const float* law_re     = (const float*)d_in[24];
  const float* law_im     = (const float*)d_in[25];
  const float* base_noise = (const float*)d_in[26];
  const float* Wu1        = (const float*)d_in[27];
  const float* bu1        = (const float*)d_in[28];
  const float* Wu2        = (const float*)d_in[29];
  const float* bu2        = (const float*)d_in[30];
  const float* noise_re   = (const float*)d_in[31];

  // --- workspace: 16 bf16-sized planes (2MB each) = 32MB --------------------
  const size_t PL16 = 1024ull * 1024ull;        // u16 per plane
  if (ws_size < 16 * PL16 * 2) return;          // too small -> zeros (diagnostic)

  u16* P = (u16*)d_ws;
  u16* Ar  = P + 0 * PL16;   u16* Ai  = P + 1 * PL16;
  u16* A2r = P + 2 * PL16;   u16* A2i = P + 3 * PL16;
  u16* A3r = P + 4 * PL16;   u16* A3i = P + 5 * PL16;
  u16* A4r = P + 6 * PL16;   u16* A4i = P + 7 * PL16;
  u16* q1r = P + 8 * PL16;   u16* q1i = P + 9 * PL16;
  u16* q2r = P + 10 * PL16;  u16* q2i = P + 11 * PL16;
  // liveness reuse (stream-ordered):
  float* Vr = (float*)(P + 0 * PL16);   // 4MB over P0,P1   (A dead after build_q)
  float* Vi = (float*)(P + 2 * PL16);   // 4MB over P2,P3   (A2 dead after build_q)
  u16* Mtr  = P + 8 * PL16;             // over q1 (dead after V-gemm)
  u16* Mti  = P + 9 * PL16;
  float* Pp = (float*)(P + 0 * PL16);   // 1MB split-K partials (V dead after build_mt)
  float* Hr = (float*)(P + 0 * PL16);   // 16MB over P0..P7 (Pp dead before xmh)
  u16* Hrb  = P + 10 * PL16;            // 8MB over q2 (dead) + P12,P13
  u16* mlp1b = P + 14 * PL16;           // 4096x256
  u16* Wu1b  = P + 15 * PL16;           // 262144 u16
  u16* Wu2b  = Wu1b + 262144;
  float* sm  = (float*)(P + 15 * PL16 + 524288);
  float* xin  = sm;                     // 16x2048
  float* proj = xin + 32768;            // 16x2048
  float* FNr  = proj + 32768;           // 16x1024
  float* FNi  = FNr + 16384;
  float* gate = FNi + 16384;            // 16x1024
  float* od_re = gate + 16384;
  float* od_im = od_re + 1024;
  float* of_re = od_im + 1024;
  float* of_im = of_re + 1024;
  float* bvar  = of_im + 1024;

  float* out0f = (float*)d_out;                       // 4096x1024 f32 (real)
  float* out1f = out0f + (size_t)4096 * 1024;         // 16x1024 f32 (real)

  // --- Cayley via degree-7 polynomial: V = q1 + q2@A^4, err <= 2.2e-3 -------
  build_a_k<<<4096, TPB, 0, stream>>>(v_raw_re, v_raw_im, Ar, Ai);
  cgemm_nt_k<0, 0><<<dim3(16, 16), TPB, 0, stream>>>(Ar, Ai, Ar, Ai, A2r, A2i,
                                                     nullptr, nullptr, nullptr, nullptr);
  cgemm_nt_k<1, 0><<<dim3(16, 16), TPB, 0, stream>>>(Ar, Ai, A2r, A2i, A3r, A3i,
                                                     nullptr, nullptr, nullptr, nullptr);
  cgemm_nt_k<1, 0><<<dim3(16, 16), TPB, 0, stream>>>(A2r, A2i, A2r, A2i, A4r, A4i,
                                                     nullptr, nullptr, nullptr, nullptr);
  build_q_k<<<4096, TPB, 0, stream>>>(Ar, Ai, A2r, A2i, A3r, A3i, q1r, q1i, q2r, q2i);
  cgemm_nt_k<1, 1><<<dim3(16, 16), TPB, 0, stream>>>(q2r, q2i, A4r, A4i,
                                                     nullptr, nullptr, q1r, q1i, Vr, Vi);
  build_mt_k<<<dim3(16, 16), TPB, 0, stream>>>(Vr, Vi, log_sigma, dft_weight, Mtr, Mti);

  // --- per-d constants + weight conversion ----------------------------------
  prep_k<<<4, TPB, 0, stream>>>(ld, lf, law_re, law_im, dt, base_noise,
                                od_re, od_im, of_re, of_im, bvar);
  conv_w_k<<<2048, TPB, 0, stream>>>(Wu1, Wu2, Wu1b, Wu2b);

  // --- B=16 chain: split-K MFMA gemms (weights read once, coalesced) -------
  sgemm16_k<<<dim3(32, 8), TPB, 0, stream>>>(xg_re, xg_im, Wi_in, Pp, 2048);
  red16_k<<<128, TPB, 0, stream>>>(Pp, bi, xin, 2048, 0);
  flux_k<<<64, TPB, 0, stream>>>(xin, flux_re, flux_im, decay_re, decay_im,
                                 FNr, FNi, out1f);
  sgemm16_k<<<dim3(32, 8), TPB, 0, stream>>>(FNr, FNi, Wo, Pp, 2048);
  red16_k<<<128, TPB, 0, stream>>>(Pp, bo, proj, 2048, 0);
  sgemm16_k<<<dim3(16, 8), TPB, 0, stream>>>(FNr, FNi, Wg, Pp, 1024);
  red16_k<<<64, TPB, 0, stream>>>(Pp, bg, gate, 1024, 1);

  // --- x_tilde = x@M fused with h_next epilogue -> Hr f32 + Hrb bf16 --------
  xmh_nt_k<<<dim3(16, 64), TPB, 0, stream>>>(x_input, Mtr, Mti, gate, proj,
                                             od_re, od_im, of_re, of_im,
                                             h_prev_re, h_prev_im, Hr, Hrb);

  // --- u-MLP (MFMA) + final noisy output ------------------------------------
  rgemm_nt_k<32, 0><<<dim3(4, 64), TPB, 0, stream>>>(Hrb, Wu1b, bu1, mlp1b, 256,
                                                     nullptr, nullptr, nullptr, nullptr);
  rgemm_nt_k<8, 1><<<dim3(16, 64), TPB, 0, stream>>>(mlp1b, Wu2b, bu2, nullptr, 1024,
                                                     Hr, noise_re, bvar, out0f);
}

// Round 9
// 225.410 us; speedup vs baseline: 11.3983x; 1.0825x over previous
//
#include <hip/hip_runtime.h>
#include <cstddef>

#define TPB 256

typedef short bf8v  __attribute__((ext_vector_type(8)));   // 8 bf16 bit-patterns
typedef float f32x4 __attribute__((ext_vector_type(4)));
typedef unsigned short u16;

#define LSTR 40      // LDS row stride in u16 (80B)
#define PLSTR 2560   // 64*LSTR
#define BUF4 10240   // 4 planes (complex NT gemm)
#define BUF3 7680    // 3 planes (xmh)
#define BUF2 5120    // 2 planes (real NT gemm)
#define BUF1 2560    // 1 plane (small gemm)

static __device__ __forceinline__ u16 f2bf(float x) {
  unsigned int u = __float_as_uint(x);
  u = (u + 0x7FFFu + ((u >> 16) & 1u)) >> 16;   // RNE f32 -> bf16
  return (u16)u;
}
static __device__ __forceinline__ float bf2f(u16 x) {
  return __uint_as_float(((unsigned int)x) << 16);
}
static __device__ __forceinline__ float sigmoidf_(float x) {
  return 1.0f / (1.0f + expf(-x));
}
static __device__ __forceinline__ bf8v neg8(bf8v a) {
  #pragma unroll
  for (int i = 0; i < 8; ++i) a[i] ^= (short)0x8000;
  return a;
}
static __device__ __forceinline__ void pack8(const float4& x, const float4& y,
                                             u16* dst) {
  unsigned int* d = (unsigned int*)dst;
  d[0] = ((unsigned)f2bf(x.y) << 16) | f2bf(x.x);
  d[1] = ((unsigned)f2bf(x.w) << 16) | f2bf(x.z);
  d[2] = ((unsigned)f2bf(y.y) << 16) | f2bf(y.x);
  d[3] = ((unsigned)f2bf(y.w) << 16) | f2bf(y.z);
}
// XCD-aware bijective block swizzle (T % 8 == 0): XCD x gets contiguous tiles.
static __device__ __forceinline__ int swz8(int flat, int T) {
  return (flat & 7) * (T >> 3) + (flat >> 3);
}

// ---------------------------------------------------------------------------
// A = (v - v^T)re + i(v + v^T)im ; N = I - A   -> bf16 planes
// ---------------------------------------------------------------------------
__global__ __launch_bounds__(TPB) void build_a_k(
    const float* __restrict__ vre, const float* __restrict__ vim,
    u16* __restrict__ Ar, u16* __restrict__ Ai,
    u16* __restrict__ Nr, u16* __restrict__ Ni)
{
  int idx = blockIdx.x * TPB + threadIdx.x;
  int i = idx >> 10, j = idx & 1023;
  float ar = vre[idx] - vre[j * 1024 + i];
  float ai = vim[idx] + vim[j * 1024 + i];
  float dg = (i == j) ? 1.0f : 0.0f;
  Ar[idx] = f2bf(ar);       Ai[idx] = f2bf(ai);
  Nr[idx] = f2bf(dg - ar);  Ni[idx] = f2bf(-ai);
}

// ---------------------------------------------------------------------------
// shared complex-NT macro body pieces (64x64 tile, 4 waves of 32x32)
// B_true from stored B-plane rows b^:
//   BNEG=0 (B-plane = A):     B_true = (-b^r, +b^i)   [A^T = -conj(A)]
//   BNEG=1 (B-plane = A^2k):  B_true = (+b^r, -b^i)   [(A^2k)^T = conj]
// ---------------------------------------------------------------------------
#define CG_PRELUDE(TILES)                                                    \
  __shared__ __align__(16) u16 lds[2 * BUF4];                                \
  int tid = threadIdx.x;                                                     \
  int lane = tid & 63;                                                       \
  int wr = (tid >> 7) & 1, wc = (tid >> 6) & 1;                              \
  int row = tid >> 2, ch = (tid & 3) << 3;                                   \
  f32x4 accR[2][2] = {};                                                     \
  f32x4 accI[2][2] = {};                                                     \
  bf8v pa[4];

#define CG_GLOAD(Apr, Api, Bpr, Bpi, k0)                                     \
  { pa[0] = *(const bf8v*)((Apr) + (size_t)(bm + row) * 1024 + (k0) + ch);   \
    pa[1] = *(const bf8v*)((Api) + (size_t)(bm + row) * 1024 + (k0) + ch);   \
    pa[2] = *(const bf8v*)((Bpr) + (size_t)(bn + row) * 1024 + (k0) + ch);   \
    pa[3] = *(const bf8v*)((Bpi) + (size_t)(bn + row) * 1024 + (k0) + ch); }

#define CG_STOLDS(buf)                                                       \
  { u16* L = lds + (buf) * BUF4 + row * LSTR + ch;                           \
    *(bf8v*)(L + 0 * PLSTR) = pa[0];                                         \
    *(bf8v*)(L + 1 * PLSTR) = pa[1];                                         \
    *(bf8v*)(L + 2 * PLSTR) = pa[2];                                         \
    *(bf8v*)(L + 3 * PLSTR) = pa[3]; }

#define CG_FRAGS(buf)                                                        \
  const u16* L = lds + (buf) * BUF4;                                         \
  int r0 = (wr * 32 + (lane & 15)) * LSTR + (lane >> 4) * 8;                 \
  int c0 = (wc * 32 + (lane & 15)) * LSTR + (lane >> 4) * 8;                 \
  bf8v ar[2], ai[2], br[2], bi[2];                                           \
  ar[0] = *(const bf8v*)(L + 0 * PLSTR + r0);                                \
  ar[1] = *(const bf8v*)(L + 0 * PLSTR + r0 + 16 * LSTR);                    \
  ai[0] = *(const bf8v*)(L + 1 * PLSTR + r0);                                \
  ai[1] = *(const bf8v*)(L + 1 * PLSTR + r0 + 16 * LSTR);                    \
  br[0] = *(const bf8v*)(L + 2 * PLSTR + c0);                                \
  br[1] = *(const bf8v*)(L + 2 * PLSTR + c0 + 16 * LSTR);                    \
  bi[0] = *(const bf8v*)(L + 3 * PLSTR + c0);                                \
  bi[1] = *(const bf8v*)(L + 3 * PLSTR + c0 + 16 * LSTR);

#define CG_MFMA_BNEG0                                                        \
  { bf8v nbr[2] = { neg8(br[0]), neg8(br[1]) };                              \
    bf8v nbi[2] = { neg8(bi[0]), neg8(bi[1]) };                              \
    _Pragma("unroll")                                                        \
    for (int mf = 0; mf < 2; ++mf)                                           \
      _Pragma("unroll")                                                      \
      for (int nf = 0; nf < 2; ++nf) {                                       \
        accR[mf][nf] = __builtin_amdgcn_mfma_f32_16x16x32_bf16(ar[mf], nbr[nf], accR[mf][nf], 0, 0, 0); \
        accR[mf][nf] = __builtin_amdgcn_mfma_f32_16x16x32_bf16(ai[mf], nbi[nf], accR[mf][nf], 0, 0, 0); \
        accI[mf][nf] = __builtin_amdgcn_mfma_f32_16x16x32_bf16(ar[mf], bi[nf],  accI[mf][nf], 0, 0, 0); \
        accI[mf][nf] = __builtin_amdgcn_mfma_f32_16x16x32_bf16(ai[mf], nbr[nf], accI[mf][nf], 0, 0, 0); \
      } }

#define CG_MFMA_BNEG1                                                        \
  { bf8v nbi[2] = { neg8(bi[0]), neg8(bi[1]) };                              \
    _Pragma("unroll")                                                        \
    for (int mf = 0; mf < 2; ++mf)                                           \
      _Pragma("unroll")                                                      \
      for (int nf = 0; nf < 2; ++nf) {                                       \
        accR[mf][nf] = __builtin_amdgcn_mfma_f32_16x16x32_bf16(ar[mf], br[nf],  accR[mf][nf], 0, 0, 0); \
        accR[mf][nf] = __builtin_amdgcn_mfma_f32_16x16x32_bf16(ai[mf], bi[nf],  accR[mf][nf], 0, 0, 0); \
        accI[mf][nf] = __builtin_amdgcn_mfma_f32_16x16x32_bf16(ar[mf], nbi[nf], accI[mf][nf], 0, 0, 0); \
        accI[mf][nf] = __builtin_amdgcn_mfma_f32_16x16x32_bf16(ai[mf], br[nf],  accI[mf][nf], 0, 0, 0); \
      } }

// --- A2 = A@A  (BNEG0, bf16 out) -------------------------------------------
__global__ __launch_bounds__(TPB) void cgemm_a2_k(
    const u16* __restrict__ Apr, const u16* __restrict__ Api,
    u16* __restrict__ Cr16, u16* __restrict__ Ci16)
{
  int flat = swz8(blockIdx.x, 256);
  int bm = (flat >> 4) * 64, bn = (flat & 15) * 64;
  CG_PRELUDE(256)
  CG_GLOAD(Apr, Api, Apr, Api, 0); CG_STOLDS(0); __syncthreads();
  int cur = 0;
  for (int t = 0; t < 32; ++t) {
    if (t < 31) CG_GLOAD(Apr, Api, Apr, Api, (t + 1) * 32);
    { CG_FRAGS(cur) CG_MFMA_BNEG0 }
    if (t < 31) CG_STOLDS(cur ^ 1);
    __syncthreads();
    cur ^= 1;
  }
  #pragma unroll
  for (int mf = 0; mf < 2; ++mf)
    #pragma unroll
    for (int nf = 0; nf < 2; ++nf) {
      int col = bn + wc * 32 + nf * 16 + (lane & 15);
      #pragma unroll
      for (int r = 0; r < 4; ++r) {
        int rowg = bm + wr * 32 + mf * 16 + (lane >> 4) * 4 + r;
        size_t o = (size_t)rowg * 1024 + col;
        Cr16[o] = f2bf(accR[mf][nf][r]);
        Ci16[o] = f2bf(accI[mf][nf][r]);
      }
    }
}

// --- batched: z=0: A4 = A2@A2 ; z=1: T1 = N@A2 + N   (BNEG1, bf16 out) -----
__global__ __launch_bounds__(TPB) void cgemm_pair_k(
    const u16* __restrict__ A2r, const u16* __restrict__ A2i,
    const u16* __restrict__ Nr2, const u16* __restrict__ Ni2,
    u16* __restrict__ A4r, u16* __restrict__ A4i,
    u16* __restrict__ T1r, u16* __restrict__ T1i)
{
  int flat = swz8(blockIdx.x, 512);
  int z = flat >> 8;
  int t8 = flat & 255;
  int bm = (t8 >> 4) * 64, bn = (t8 & 15) * 64;
  const u16* Apr = z ? Nr2 : A2r;
  const u16* Api = z ? Ni2 : A2i;
  u16* Cr16 = z ? T1r : A4r;
  u16* Ci16 = z ? T1i : A4i;
  CG_PRELUDE(512)
  CG_GLOAD(Apr, Api, A2r, A2i, 0); CG_STOLDS(0); __syncthreads();
  int cur = 0;
  for (int t = 0; t < 32; ++t) {
    if (t < 31) CG_GLOAD(Apr, Api, A2r, A2i, (t + 1) * 32);
    { CG_FRAGS(cur) CG_MFMA_BNEG1 }
    if (t < 31) CG_STOLDS(cur ^ 1);
    __syncthreads();
    cur ^= 1;
  }
  #pragma unroll
  for (int mf = 0; mf < 2; ++mf)
    #pragma unroll
    for (int nf = 0; nf < 2; ++nf) {
      int col = bn + wc * 32 + nf * 16 + (lane & 15);
      #pragma unroll
      for (int r = 0; r < 4; ++r) {
        int rowg = bm + wr * 32 + mf * 16 + (lane >> 4) * 4 + r;
        size_t o = (size_t)rowg * 1024 + col;
        float vr = accR[mf][nf][r], vi = accI[mf][nf][r];
        if (z) { vr += bf2f(Nr2[o]); vi += bf2f(Ni2[o]); }   // +N
        Cr16[o] = f2bf(vr);
        Ci16[o] = f2bf(vi);
      }
    }
}

// --- V = 2*(T1@A4) + 2*T1 - I   (BNEG1, f32 out) ---------------------------
__global__ __launch_bounds__(TPB) void cgemm_v_k(
    const u16* __restrict__ T1r, const u16* __restrict__ T1i,
    const u16* __restrict__ A4r, const u16* __restrict__ A4i,
    float* __restrict__ Vr, float* __restrict__ Vi)
{
  int flat = swz8(blockIdx.x, 256);
  int bm = (flat >> 4) * 64, bn = (flat & 15) * 64;
  CG_PRELUDE(256)
  CG_GLOAD(T1r, T1i, A4r, A4i, 0); CG_STOLDS(0); __syncthreads();
  int cur = 0;
  for (int t = 0; t < 32; ++t) {
    if (t < 31) CG_GLOAD(T1r, T1i, A4r, A4i, (t + 1) * 32);
    { CG_FRAGS(cur) CG_MFMA_BNEG1 }
    if (t < 31) CG_STOLDS(cur ^ 1);
    __syncthreads();
    cur ^= 1;
  }
  #pragma unroll
  for (int mf = 0; mf < 2; ++mf)
    #pragma unroll
    for (int nf = 0; nf < 2; ++nf) {
      int col = bn + wc * 32 + nf * 16 + (lane & 15);
      #pragma unroll
      for (int r = 0; r < 4; ++r) {
        int rowg = bm + wr * 32 + mf * 16 + (lane >> 4) * 4 + r;
        size_t o = (size_t)rowg * 1024 + col;
        float dg = (rowg == col) ? 1.0f : 0.0f;
        Vr[o] = 2.0f * accR[mf][nf][r] + 2.0f * bf2f(T1r[o]) - dg;
        Vi[o] = 2.0f * accI[mf][nf][r] + 2.0f * bf2f(T1i[o]);
      }
    }
}

// ---------------------------------------------------------------------------
// Mt[d][k] = bf16( V[k][d]*exp(ls[d])*(1-alpha) + F[k][d]*alpha/32 )
// ---------------------------------------------------------------------------
__global__ __launch_bounds__(TPB) void build_mt_k(
    const float* __restrict__ Vr, const float* __restrict__ Vi,
    const float* __restrict__ log_sigma, const float* __restrict__ dft_weight,
    u16* __restrict__ Mtr, u16* __restrict__ Mti)
{
  __shared__ float Tr[64][65], Ti[64][65];
  int tid = threadIdx.x;
  int k0 = blockIdx.x * 64, d0 = blockIdx.y * 64;
  int c = tid & 63, r4 = tid >> 6;
  for (int p = 0; p < 16; ++p) {
    int r = r4 + p * 4;                       // local k index
    Tr[r][c] = Vr[(size_t)(k0 + r) * 1024 + d0 + c];
    Ti[r][c] = Vi[(size_t)(k0 + r) * 1024 + d0 + c];
  }
  __syncthreads();
  float alpha = sigmoidf_(dft_weight[0]);
  const float isq = 0.03125f * alpha;
  for (int p = 0; p < 16; ++p) {
    int dl = r4 + p * 4;                      // local d index (output row)
    int d = d0 + dl, k = k0 + c;
    float w1 = expf(log_sigma[d]) * (1.0f - alpha);
    int mm = (k * d) & 1023;
    float ang = -6.283185307179586f * (float)mm * (1.0f / 1024.0f);
    float sn, cs;
    sincosf(ang, &sn, &cs);
    size_t o = (size_t)d * 1024 + k;
    Mtr[o] = f2bf(Tr[c][dl] * w1 + cs * isq);
    Mti[o] = f2bf(Ti[c][dl] * w1 + sn * isq);
  }
}

// ---------------------------------------------------------------------------
// X f32 -> bf16 plane (vectorized, once)
// ---------------------------------------------------------------------------
__global__ __launch_bounds__(TPB) void xconv_k(
    const float* __restrict__ X, u16* __restrict__ Xb)
{
  int idx = (blockIdx.x * TPB + threadIdx.x) << 3;    // 8 per thread
  float4 a = *(const float4*)(X + idx);
  float4 b = *(const float4*)(X + idx + 4);
  u16 tmp[8];
  pack8(a, b, tmp);
  *(bf8v*)(Xb + idx) = *(bf8v*)tmp;
}

// ---------------------------------------------------------------------------
// per-d constants: op_decay, op_forcing, base_var
// ---------------------------------------------------------------------------
__global__ __launch_bounds__(TPB) void prep_k(
    const float* __restrict__ ld, const float* __restrict__ lf,
    const float* __restrict__ law_re, const float* __restrict__ law_im,
    const float* __restrict__ dt, const float* __restrict__ base_noise,
    float* __restrict__ od_re, float* __restrict__ od_im,
    float* __restrict__ of_re, float* __restrict__ of_im,
    float* __restrict__ bvar)
{
  int d = blockIdx.x * TPB + threadIdx.x;
  float dtr = dt[0];                              // DT_REF = 1.0
  float lre = tanhf(-expf(ld[d]) + law_re[d]) * 0.3f;
  float lim = lf[d] + law_im[d];
  float er = expf(lre * dtr);
  float sn, cs;
  sincosf(lim * dtr, &sn, &cs);
  float odr = er * cs, odi = er * sn;
  od_re[d] = odr;  od_im[d] = odi;
  float numr = odr - 1.0f, numi = odi;
  float denr = lre + 1e-8f, deni = lim;
  float inv = 1.0f / (denr * denr + deni * deni);
  of_re[d] = (numr * denr + numi * deni) * inv;
  of_im[d] = (numi * denr - numr * deni) * inv;
  float bn = base_noise[0];
  float bv = bn * bn * expm1f(2.0f * lre * dtr) / (2.0f * lre + 1e-8f);
  bvar[d] = fmaxf(bv, 0.0f);
}

// ---------------------------------------------------------------------------
// Wu1, Wu2 f32 -> bf16 planes
// ---------------------------------------------------------------------------
__global__ __launch_bounds__(TPB) void conv_w_k(
    const float* __restrict__ Wu1, const float* __restrict__ Wu2,
    u16* __restrict__ Wu1b, u16* __restrict__ Wu2b)
{
  int idx = blockIdx.x * TPB + threadIdx.x;     // 2 * 262144
  if (idx < 262144) Wu1b[idx] = f2bf(Wu1[idx]);
  else              Wu2b[idx - 262144] = f2bf(Wu2[idx - 262144]);
}

// ---------------------------------------------------------------------------
// M=16 split-K MFMA GEMM (partials) ; reduce adds bias (+sigmoid)
// ---------------------------------------------------------------------------
__global__ __launch_bounds__(TPB) void sgemm16_k(
    const float* __restrict__ A0, const float* __restrict__ A1,
    const float* __restrict__ Bw, float* __restrict__ Pp, int N)
{
  __shared__ __align__(16) u16 lds[2 * BUF1];
  int tid = threadIdx.x;
  int c0 = blockIdx.x * 64;
  int kbase = blockIdx.y * 256;
  int lane = tid & 63;
  int w = tid >> 6;
  int row = tid >> 2, kq = (tid & 3) << 3;

  f32x4 acc = {};
  float4 pb0, pb1;

  auto gload = [&](int k0) {
    const float* p = Bw + (size_t)(c0 + row) * 2048 + k0 + kq;
    pb0 = *(const float4*)p; pb1 = *(const float4*)(p + 4);
  };
  auto stolds = [&](int buf) {
    pack8(pb0, pb1, lds + buf * BUF1 + row * LSTR + kq);
  };
  auto compute = [&](int buf, int k0) {
    int ar = lane & 15;
    int ko = (lane >> 4) * 8;
    const float* ap = (k0 < 1024) ? (A0 + (size_t)ar * 1024 + k0 + ko)
                                  : (A1 + (size_t)ar * 1024 + k0 + ko - 1024);
    float4 a0 = *(const float4*)ap, a1 = *(const float4*)(ap + 4);
    u16 abuf[8];
    pack8(a0, a1, abuf);
    bf8v af = *(bf8v*)abuf;
    const u16* L = lds + buf * BUF1;
    bf8v bfr = *(const bf8v*)(L + (w * 16 + (lane & 15)) * LSTR + ko);
    acc = __builtin_amdgcn_mfma_f32_16x16x32_bf16(af, bfr, acc, 0, 0, 0);
  };

  gload(kbase); stolds(0); __syncthreads();
  int cur = 0;
  for (int t = 0; t < 8; ++t) {
    int k0 = kbase + t * 32;
    if (t < 7) gload(k0 + 32);
    compute(cur, k0);
    if (t < 7) stolds(cur ^ 1);
    __syncthreads();
    cur ^= 1;
  }

  int c = c0 + w * 16 + (lane & 15);
  #pragma unroll
  for (int r = 0; r < 4; ++r) {
    int rr = (lane >> 4) * 4 + r;
    Pp[((size_t)blockIdx.y * 16 + rr) * N + c] = acc[r];
  }
}

__global__ __launch_bounds__(TPB) void red16_k(
    const float* __restrict__ Pp, const float* __restrict__ bias,
    float* __restrict__ out, int N, int act)
{
  int idx = blockIdx.x * TPB + threadIdx.x;   // 16*N
  int c = idx & (N - 1);
  float v = bias[c];
  #pragma unroll
  for (int s = 0; s < 8; ++s) v += Pp[(size_t)s * 16 * N + idx];
  if (act == 1) v = sigmoidf_(v);
  out[idx] = v;
}

// ---------------------------------------------------------------------------
// flux_next = flux*fdecay + update ; FN planes + f32 output 1 = Re(flux_next)
// ---------------------------------------------------------------------------
__global__ __launch_bounds__(TPB) void flux_k(
    const float* __restrict__ xin,
    const float* __restrict__ flux_re, const float* __restrict__ flux_im,
    const float* __restrict__ decay_re, const float* __restrict__ decay_im,
    float* __restrict__ FNr, float* __restrict__ FNi,
    float* __restrict__ out1)
{
  int idx = blockIdx.x * TPB + threadIdx.x;     // 16 * 1024
  int b = idx >> 10, d = idx & 1023;
  float fdr = sigmoidf_(decay_re[d]);
  float fdi = decay_im[d];
  float fr = flux_re[idx], fi = flux_im[idx];
  float ur = xin[b * 2048 + d], ui = xin[b * 2048 + 1024 + d];
  float nr = fr * fdr - fi * fdi + ur;
  float ni = fr * fdi + fi * fdr + ui;
  FNr[idx] = nr;  FNi[idx] = ni;
  out1[idx] = nr;                                // f32, real part only
}

// ---------------------------------------------------------------------------
// x_tilde = Xb @ M + h_next epilogue -> Hrb bf16 only
// ---------------------------------------------------------------------------
__global__ __launch_bounds__(TPB) void xmh_nt_k(
    const u16* __restrict__ Xb,
    const u16* __restrict__ Mtr, const u16* __restrict__ Mti,
    const float* __restrict__ gate, const float* __restrict__ proj,
    const float* __restrict__ od_re, const float* __restrict__ od_im,
    const float* __restrict__ of_re, const float* __restrict__ of_im,
    const float* __restrict__ hp_re, const float* __restrict__ hp_im,
    u16* __restrict__ Hrb)
{
  __shared__ __align__(16) u16 lds[2 * BUF3];
  int flat = swz8(blockIdx.x, 1024);
  int bm = (flat >> 4) * 64, bn = (flat & 15) * 64;
  int tid = threadIdx.x;
  int lane = tid & 63;
  int wr = (tid >> 7) & 1, wc = (tid >> 6) & 1;
  int row = tid >> 2, ch = (tid & 3) << 3;

  f32x4 accR[2][2] = {};
  f32x4 accI[2][2] = {};
  bf8v pa[3];

  auto gload = [&](int k0) {
    pa[0] = *(const bf8v*)(Xb  + (size_t)(bm + row) * 1024 + k0 + ch);
    pa[1] = *(const bf8v*)(Mtr + (size_t)(bn + row) * 1024 + k0 + ch);
    pa[2] = *(const bf8v*)(Mti + (size_t)(bn + row) * 1024 + k0 + ch);
  };
  auto stolds = [&](int buf) {
    u16* L = lds + buf * BUF3 + row * LSTR + ch;
    *(bf8v*)(L + 0 * PLSTR) = pa[0];
    *(bf8v*)(L + 1 * PLSTR) = pa[1];
    *(bf8v*)(L + 2 * PLSTR) = pa[2];
  };
  auto compute = [&](int buf) {
    const u16* L = lds + buf * BUF3;
    int r0 = (wr * 32 + (lane & 15)) * LSTR + (lane >> 4) * 8;
    int c0 = (wc * 32 + (lane & 15)) * LSTR + (lane >> 4) * 8;
    bf8v a[2], br[2], bi[2];
    a[0]  = *(const bf8v*)(L + 0 * PLSTR + r0);
    a[1]  = *(const bf8v*)(L + 0 * PLSTR + r0 + 16 * LSTR);
    br[0] = *(const bf8v*)(L + 1 * PLSTR + c0);
    br[1] = *(const bf8v*)(L + 1 * PLSTR + c0 + 16 * LSTR);
    bi[0] = *(const bf8v*)(L + 2 * PLSTR + c0);
    bi[1] = *(const bf8v*)(L + 2 * PLSTR + c0 + 16 * LSTR);
    #pragma unroll
    for (int mf = 0; mf < 2; ++mf)
      #pragma unroll
      for (int nf = 0; nf < 2; ++nf) {
        accR[mf][nf] = __builtin_amdgcn_mfma_f32_16x16x32_bf16(a[mf], br[nf], accR[mf][nf], 0, 0, 0);
        accI[mf][nf] = __builtin_amdgcn_mfma_f32_16x16x32_bf16(a[mf], bi[nf], accI[mf][nf], 0, 0, 0);
      }
  };

  gload(0); stolds(0); __syncthreads();
  int cur = 0;
  for (int t = 0; t < 32; ++t) {
    if (t < 31) gload((t + 1) * 32);
    compute(cur);
    if (t < 31) stolds(cur ^ 1);
    __syncthreads();
    cur ^= 1;
  }

  #pragma unroll
  for (int mf = 0; mf < 2; ++mf)
    #pragma unroll
    for (int nf = 0; nf < 2; ++nf) {
      int c = bn + wc * 32 + nf * 16 + (lane & 15);
      #pragma unroll
      for (int r = 0; r < 4; ++r) {
        int t = bm + wr * 32 + mf * 16 + (lane >> 4) * 4 + r;
        int b = t >> 8;                         // 64-row tile never straddles batch
        float g  = gate[b * 1024 + c];
        float sr = proj[b * 2048 + c];
        float si = proj[b * 2048 + 1024 + c];
        float fr = accR[mf][nf][r] * g + sr * (1.0f - g);
        float fi = accI[mf][nf][r] * g + si * (1.0f - g);
        float odr = od_re[c], odi = od_im[c];
        float ofr = of_re[c], ofi = of_im[c];
        size_t off = (size_t)t * 1024 + c;
        float pr = hp_re[off], pi = hp_im[off];
        Hrb[off] = f2bf(pr * odr - pi * odi + fr * ofr - fi * ofi);
      }
    }
}

// ---------------------------------------------------------------------------
// real NT GEMM, bf16: C = A@B^T.  KI = K/32.
// EPI=0 (mlp1): silu->bf16.  EPI=1 (final): softplus->noise; out0 = Hrb+n*sc
// ---------------------------------------------------------------------------
template<int KI, int EPI>
__global__ __launch_bounds__(TPB) void rgemm_nt_k(
    const u16* __restrict__ A, const u16* __restrict__ B,
    const float* __restrict__ bias,
    u16* __restrict__ C16, int N,
    const u16* __restrict__ Hrb, const float* __restrict__ nre,
    const float* __restrict__ bvar, float* __restrict__ out0)
{
  __shared__ __align__(16) u16 lds[2 * BUF2];
  const int K = KI * 32;
  int tid = threadIdx.x;
  int bm = blockIdx.y * 64, bn = blockIdx.x * 64;
  int lane = tid & 63;
  int wr = (tid >> 7) & 1, wc = (tid >> 6) & 1;
  int row = tid >> 2, ch = (tid & 3) << 3;

  f32x4 acc[2][2] = {};
  bf8v pa[2];

  auto gload = [&](int k0) {
    pa[0] = *(const bf8v*)(A + (size_t)(bm + row) * K + k0 + ch);
    pa[1] = *(const bf8v*)(B + (size_t)(bn + row) * K + k0 + ch);
  };
  auto stolds = [&](int buf) {
    u16* L = lds + buf * BUF2 + row * LSTR + ch;
    *(bf8v*)(L + 0 * PLSTR) = pa[0];
    *(bf8v*)(L + 1 * PLSTR) = pa[1];
  };
  auto compute = [&](int buf) {
    const u16* L = lds + buf * BUF2;
    int r0 = (wr * 32 + (lane & 15)) * LSTR + (lane >> 4) * 8;
    int c0 = (wc * 32 + (lane & 15)) * LSTR + (lane >> 4) * 8;
    bf8v a[2], b[2];
    a[0] = *(const bf8v*)(L + 0 * PLSTR + r0);
    a[1] = *(const bf8v*)(L + 0 * PLSTR + r0 + 16 * LSTR);
    b[0] = *(const bf8v*)(L + 1 * PLSTR + c0);
    b[1] = *(const bf8v*)(L + 1 * PLSTR + c0 + 16 * LSTR);
    #pragma unroll
    for (int mf = 0; mf < 2; ++mf)
      #pragma unroll
      for (int nf = 0; nf < 2; ++nf)
        acc[mf][nf] = __builtin_amdgcn_mfma_f32_16x16x32_bf16(a[mf], b[nf], acc[mf][nf], 0, 0, 0);
  };

  gload(0); stolds(0); __syncthreads();
  int cur = 0;
  for (int t = 0; t < KI; ++t) {
    if (t < KI - 1) gload((t + 1) * 32);
    compute(cur);
    if (t < KI - 1) stolds(cur ^ 1);
    __syncthreads();
    cur ^= 1;
  }

  #pragma unroll
  for (int mf = 0; mf < 2; ++mf)
    #pragma unroll
    for (int nf = 0; nf < 2; ++nf) {
      int c = bn + wc * 32 + nf * 16 + (lane & 15);
      #pragma unroll
      for (int r = 0; r < 4; ++r) {
        int t = bm + wr * 32 + mf * 16 + (lane >> 4) * 4 + r;
        float v = acc[mf][nf][r] + bias[c];
        if constexpr (EPI == 0) {
          v = v * sigmoidf_(v);                       // silu
          C16[(size_t)t * N + c] = f2bf(v);
        } else {
          float u = (v > 20.0f) ? v : log1pf(expf(v));    // softplus
          float sc = sqrtf(bvar[c] * u) * 0.7071067811865476f;
          size_t off = (size_t)t * 1024 + c;
          out0[off] = bf2f(Hrb[off]) + nre[off] * sc;
        }
      }
    }
}

// ---------------------------------------------------------------------------
extern "C" void kernel_launch(void* const* d_in, const int* in_sizes, int n_in,
                              void* d_out, int out_size, void* d_ws, size_t ws_size,
                              hipStream_t stream) {
  (void)in_sizes; (void)n_in; (void)out_size;

  const float* x_input    = (const float*)d_in[0];
  const float* h_prev_re  = (const float*)d_in[1];
  const float* h_prev_im  = (const float*)d_in[2];
  const float* xg_re      = (const float*)d_in[3];
  const float* xg_im      = (const float*)d_in[4];
  const float* flux_re    = (const float*)d_in[5];
  const float* flux_im    = (const float*)d_in[6];
  const float* dt         = (const float*)d_in[7];
  const float* v_raw_re   = (const float*)d_in[10];
  const float* v_raw_im   = (const float*)d_in[11];
  const float* log_sigma  = (const float*)d_in[12];
  const float* dft_weight = (const float*)d_in[13];
  const float* decay_re   = (const float*)d_in[14];
  const float* decay_im   = (const float*)d_in[15];
  const float* Wi_in      = (const float*)d_in[16];
  const float* bi         = (const float*)d_in[17];
  const float* Wo         = (const float*)d_in[18];
  const float* bo         = (const float*)d_in[19];
  const float* Wg         = (const float*)d_in[20];
  const float* bg         = (const float*)d_in[21];
  const float* ld         = (const float*)d_in[22];
  const float* lf         = (const float*)d_in[23];
  const float* law_re     = (const float*)d_in[24];
  const float* law_im     = (const float*)d_in[25];
  const float* base_noise = (const float*)d_in[26];
  const float* Wu1        = (const float*)d_in[27];
  const float* bu1        = (const float*)d_in[28];
  const float* Wu2        = (const float*)d_in[29];
  const float* bu2        = (const float*)d_in[30];
  const float* noise_re   = (const float*)d_in[31];

  // --- workspace: 16 bf16-sized planes (2MB each) = 32MB --------------------
  const size_t PL16 = 1024ull * 1024ull;        // u16 per plane
  if (ws_size < 16 * PL16 * 2) return;          // too small -> zeros (diagnostic)

  u16* P = (u16*)d_ws;
  u16* Ar  = P + 0 * PL16;   u16* Ai  = P + 1 * PL16;   // A       (dead after A2)
  u16* Nr  = P + 2 * PL16;   u16* Ni  = P + 3 * PL16;   // N = I-A (dead after pair)
  u16* A2r = P + 4 * PL16;   u16* A2i = P + 5 * PL16;   // dead after pair
  u16* A4r = P + 6 * PL16;   u16* A4i = P + 7 * PL16;   // dead after V
  u16* T1r = P + 8 * PL16;   u16* T1i = P + 9 * PL16;   // dead after V
  // liveness reuse (stream-ordered):
  float* Vr = (float*)(P + 0 * PL16);   // 8MB over P0..P3 (A,N dead)
  float* Vi = (float*)(P + 2 * PL16);
  u16* Mtr  = P + 8 * PL16;             // over T1 (dead after V)
  u16* Mti  = P + 9 * PL16;
  u16* Xb   = P + 4 * PL16;             // 8MB over A2,A4 (dead after V)
  float* Pp = (float*)(P + 0 * PL16);   // 1MB split-K partials (V dead after build_mt)
  u16* Hrb  = P + 10 * PL16;            // 8MB, P10..P13
  u16* mlp1b = P + 14 * PL16;           // 4096x256
  u16* Wu1b  = P + 15 * PL16;           // 262144 u16
  u16* Wu2b  = Wu1b + 262144;
  float* sm  = (float*)(P + 15 * PL16 + 524288);
  float* xin  = sm;                     // 16x2048
  float* proj = xin + 32768;            // 16x2048
  float* FNr  = proj + 32768;           // 16x1024
  float* FNi  = FNr + 16384;
  float* gate = FNi + 16384;            // 16x1024
  float* od_re = gate + 16384;
  float* od_im = od_re + 1024;
  float* of_re = od_im + 1024;
  float* of_im = of_re + 1024;
  float* bvar  = of_im + 1024;

  float* out0f = (float*)d_out;                       // 4096x1024 f32 (real)
  float* out1f = out0f + (size_t)4096 * 1024;         // 16x1024 f32 (real)

  // --- Cayley: V = 2*(I-A)(I+A^2)(I+A^4) - I, err <= 2.2e-3 -----------------
  build_a_k<<<4096, TPB, 0, stream>>>(v_raw_re, v_raw_im, Ar, Ai, Nr, Ni);
  cgemm_a2_k<<<256, TPB, 0, stream>>>(Ar, Ai, A2r, A2i);                 // A2 = A@A
  cgemm_pair_k<<<512, TPB, 0, stream>>>(A2r, A2i, Nr, Ni,                // A4 = A2@A2
                                        A4r, A4i, T1r, T1i);             // T1 = N@A2+N
  cgemm_v_k<<<256, TPB, 0, stream>>>(T1r, T1i, A4r, A4i, Vr, Vi);        // V
  build_mt_k<<<dim3(16, 16), TPB, 0, stream>>>(Vr, Vi, log_sigma, dft_weight, Mtr, Mti);
  xconv_k<<<2048, TPB, 0, stream>>>(x_input, Xb);

  // --- per-d constants + weight conversion ----------------------------------
  prep_k<<<4, TPB, 0, stream>>>(ld, lf, law_re, law_im, dt, base_noise,
                                od_re, od_im, of_re, of_im, bvar);
  conv_w_k<<<2048, TPB, 0, stream>>>(Wu1, Wu2, Wu1b, Wu2b);

  // --- B=16 chain: split-K MFMA gemms ---------------------------------------
  sgemm16_k<<<dim3(32, 8), TPB, 0, stream>>>(xg_re, xg_im, Wi_in, Pp, 2048);
  red16_k<<<128, TPB, 0, stream>>>(Pp, bi, xin, 2048, 0);
  flux_k<<<64, TPB, 0, stream>>>(xin, flux_re, flux_im, decay_re, decay_im,
                                 FNr, FNi, out1f);
  sgemm16_k<<<dim3(32, 8), TPB, 0, stream>>>(FNr, FNi, Wo, Pp, 2048);
  red16_k<<<128, TPB, 0, stream>>>(Pp, bo, proj, 2048, 0);
  sgemm16_k<<<dim3(16, 8), TPB, 0, stream>>>(FNr, FNi, Wg, Pp, 1024);
  red16_k<<<64, TPB, 0, stream>>>(Pp, bg, gate, 1024, 1);

  // --- x_tilde = Xb@M fused with h_next epilogue -> Hrb bf16 ----------------
  xmh_nt_k<<<1024, TPB, 0, stream>>>(Xb, Mtr, Mti, gate, proj,
                                     od_re, od_im, of_re, of_im,
                                     h_prev_re, h_prev_im, Hrb);

  // --- u-MLP (MFMA) + final noisy output ------------------------------------
  rgemm_nt_k<32, 0><<<dim3(4, 64), TPB, 0, stream>>>(Hrb, Wu1b, bu1, mlp1b, 256,
                                                     nullptr, nullptr, nullptr, nullptr);
  rgemm_nt_k<8, 1><<<dim3(16, 64), TPB, 0, stream>>>(mlp1b, Wu2b, bu2, nullptr, 1024,
                                                     Hrb, noise_re, bvar, out0f);
}